// Round 13
// baseline (315.726 us; speedup 1.0000x reference)
//
#include <hip/hip_runtime.h>
#include <hip/hip_bf16.h>
#include <cstddef>

typedef _Float16 h2 __attribute__((ext_vector_type(2)));
typedef _Float16 half8 __attribute__((ext_vector_type(8)));
typedef float f32x4 __attribute__((ext_vector_type(4)));

__device__ __forceinline__ float fast_tanh(float x) {
    float e = __expf(2.0f * x);
    return 1.0f - 2.0f / (e + 1.0f);
}

__device__ __forceinline__ float fdot2u(unsigned int a, unsigned int b, float c) {
    union U { unsigned int u; h2 h; };
    U ua; ua.u = a;
    U ub; ub.u = b;
    return __builtin_amdgcn_fdot2(ua.h, ub.h, c, false);
}

__device__ __forceinline__ unsigned int pkh(float a, float b) {
    union { _Float16 h; unsigned short u; } x, y;
    x.h = (_Float16)a; y.h = (_Float16)b;
    return ((unsigned int)y.u << 16) | (unsigned int)x.u;
}

// K-slot permutation for conv1 MFMA (K=32 per ic) — round-5 verified:
// pair p (slots 2p,2p+1): p<10: taps (row p>>1, cols 2(p&1), 2(p&1)+1)
//                         p=10..14: (row p-10, col 4) + zero ; p=15: zero,zero
#define S1D 33  // s1p row stride in dwords

// ---------------------------------------------------------------------------
// pack: f0pk (conv0 dot2 pairs) + w1mf (conv1 MFMA A-frags) — round-5 verbatim
__global__ void pack_weights(const float* __restrict__ c1_w,
                             const float* __restrict__ filters,
                             unsigned int* __restrict__ f0pk,   // [16][5][6]
                             unsigned int* __restrict__ w1mf) { // [16ic][4h][16oc][4d]
    int t = blockIdx.x * blockDim.x + threadIdx.x;
    if (t < 80) {
        int oc = t / 5, ky = t % 5;
        const float* w = filters + oc * 25 + ky * 5;
        unsigned int* d = f0pk + oc * 30 + ky * 6;
        d[0] = pkh(w[0], w[1]); d[1] = pkh(w[2], w[3]); d[2] = pkh(w[4], 0.f);
        d[3] = pkh(0.f, w[0]); d[4] = pkh(w[1], w[2]); d[5] = pkh(w[3], w[4]);
    } else if (t >= 256 && t < 256 + 4096) {
        int g = t - 256;
        int d = g & 3, oc = (g >> 2) & 15, h = (g >> 6) & 3, ic = g >> 8;
        int p = 4 * h + d;
        float w0 = 0.f, w1 = 0.f;
        if (oc < 6) {
            const float* w = c1_w + (oc * 16 + ic) * 25;
            if (p < 10) {
                int ty = p >> 1, txb = 2 * (p & 1);
                w0 = w[ty * 5 + txb]; w1 = w[ty * 5 + txb + 1];
            } else if (p < 15) {
                w0 = w[(p - 10) * 5 + 4];
            }
        }
        w1mf[g] = pkh(w0, w1);
    }
}

// ---------------------------------------------------------------------------
// Kernel A (round-11 verbatim): conv0 dot2 + tanh -> pair-dup f16 LDS;
// conv1 via MFMA 16x16x32_f16 + bias + tanh + avgpool2 -> out2.
// LDS: s1p 67584 B + xs2 2736 B = 70320 B -> 2 blocks/CU, 16 waves/CU.
__global__ __launch_bounds__(512, 2) void lenet_front(
    const float* __restrict__ x,            // [B,1,32,32]
    const unsigned int* __restrict__ f0pk,
    const unsigned int* __restrict__ w1mf,
    const float* __restrict__ c1_b,         // [6]
    float* __restrict__ out2)               // [B,6,14,14]
{
    __shared__ unsigned int xs2[36 * 19];       // padded input, f16 pairs
    __shared__ unsigned int s1p[16 * 32 * S1D]; // tanh(conv0): dword x = (px x, px x+1)

    const int b = blockIdx.x;
    const int tid = threadIdx.x;
    const float* xb = x + (size_t)b * 1024;

    for (int i = tid; i < 36 * 19; i += 512) xs2[i] = 0u;
    __syncthreads();
    // P0: one element per thread (512 = 32 rows x 16 pair-cols)
    {
        int r = tid >> 4, c2 = tid & 15;
        const float2 v = *(const float2*)(xb + r * 32 + c2 * 2);
        xs2[(r + 2) * 19 + c2 + 1] = pkh(v.x, v.y);
    }
    __syncthreads();

    // ---- Phase A: conv0 + tanh, 5 px/thread, pair-dup dwords.
    // 256 (y,xg) tasks x 2 oc-halves (tid>>8 selects oc 0..7 / 8..15).
    {
        const int tt = tid & 255;
        const int y = tt >> 3;
        const int xg = tt & 7;
        const int x0 = xg * 4;
        const int x0h = xg * 2;
        const int oc0 = (tid >> 8) * 8;
        unsigned int win2[5][5];
#pragma unroll
        for (int i = 0; i < 5; i++) {
            const unsigned int* pr = &xs2[(y + i) * 19 + x0h];
#pragma unroll
            for (int q = 0; q < 5; q++) win2[i][q] = pr[q];
        }
#pragma unroll 1
        for (int oc = oc0; oc < oc0 + 8; oc++) {
            const unsigned int* fw = f0pk + oc * 30;  // uniform -> s_load
            float a0 = 0.f, a1 = 0.f, a2 = 0.f, a3 = 0.f, a4 = 0.f;
#pragma unroll
            for (int ky = 0; ky < 5; ky++) {
                unsigned int w01 = fw[ky * 6 + 0], w23 = fw[ky * 6 + 1], w4z = fw[ky * 6 + 2];
                unsigned int zw0 = fw[ky * 6 + 3], w12 = fw[ky * 6 + 4], w34 = fw[ky * 6 + 5];
                a0 = fdot2u(w01, win2[ky][0], a0);
                a0 = fdot2u(w23, win2[ky][1], a0);
                a0 = fdot2u(w4z, win2[ky][2], a0);
                a1 = fdot2u(zw0, win2[ky][0], a1);
                a1 = fdot2u(w12, win2[ky][1], a1);
                a1 = fdot2u(w34, win2[ky][2], a1);
                a2 = fdot2u(w01, win2[ky][1], a2);
                a2 = fdot2u(w23, win2[ky][2], a2);
                a2 = fdot2u(w4z, win2[ky][3], a2);
                a3 = fdot2u(zw0, win2[ky][1], a3);
                a3 = fdot2u(w12, win2[ky][2], a3);
                a3 = fdot2u(w34, win2[ky][3], a3);
                a4 = fdot2u(w01, win2[ky][2], a4);
                a4 = fdot2u(w23, win2[ky][3], a4);
                a4 = fdot2u(w4z, win2[ky][4], a4);
            }
            float t0 = fast_tanh(a0), t1 = fast_tanh(a1), t2 = fast_tanh(a2);
            float t3 = fast_tanh(a3), t4 = fast_tanh(a4);
            int base = (oc * 32 + y) * S1D + x0;
            s1p[base + 0] = pkh(t0, t1);
            s1p[base + 1] = pkh(t1, t2);
            s1p[base + 2] = pkh(t2, t3);
            s1p[base + 3] = pkh(t3, t4);
        }
    }
    __syncthreads();

    // ---- Phase B (round-5 verbatim, 8-wave schedule): conv1 MFMA + epilogue
    const int lane = tid & 63;
    const int wid = tid >> 6;        // 0..7
    const int h = lane >> 4;
    const int c = lane & 15;

    half8 af[16];
    const half8* w1v = (const half8*)w1mf;
#pragma unroll
    for (int ks = 0; ks < 16; ks++) af[ks] = w1v[(ks * 4 + h) * 16 + c];

    int offd[4];
#pragma unroll
    for (int pl = 0; pl < 4; pl++) {
        int p = 4 * h + pl;
        int pp = (p < 15) ? p : 14;
        int ty = (pp < 10) ? (pp >> 1) : (pp - 10);
        int tx = (pp < 10) ? ((pp & 1) * 2) : 4;
        offd[pl] = ty * S1D + tx + c;
    }

    float bias_l[4];
#pragma unroll
    for (int r = 0; r < 4; r++) {
        int rr = 4 * h + r;
        bias_l[r] = c1_b[rr < 6 ? rr : 5];
    }

#pragma unroll 1
    for (int q = wid; q < 28; q += 8) {
        const int py = q >> 1;
        const int xh = q & 1;
        const int x0 = 12 * xh;
        const int yy = 2 * py;

        f32x4 acc0 = {0.f, 0.f, 0.f, 0.f};
        f32x4 acc1 = {0.f, 0.f, 0.f, 0.f};
#pragma unroll
        for (int ks = 0; ks < 16; ks++) {
            const int bb0 = (ks * 32 + yy) * S1D + x0;
            union H8 { unsigned int u[4]; half8 hv; };
            H8 B0, B1;
#pragma unroll
            for (int pl = 0; pl < 4; pl++) {
                B0.u[pl] = s1p[bb0 + offd[pl]];
                B1.u[pl] = s1p[bb0 + S1D + offd[pl]];
            }
            acc0 = __builtin_amdgcn_mfma_f32_16x16x32_f16(af[ks], B0.hv, acc0, 0, 0, 0);
            acc1 = __builtin_amdgcn_mfma_f32_16x16x32_f16(af[ks], B1.hv, acc1, 0, 0, 0);
        }
#pragma unroll
        for (int r = 0; r < 4; r++) {
            int rr = 4 * h + r;
            float t = fast_tanh(acc0[r] + bias_l[r]) + fast_tanh(acc1[r] + bias_l[r]);
            t += __shfl_xor(t, 1);
            int pq = (c >> 1) + 6 * xh;
            bool ok = (rr < 6) && ((c & 1) == 0) && (xh ? (pq >= 7) : (pq <= 6));
            if (ok) out2[((size_t)b * 6 + rr) * 196 + py * 14 + pq] = 0.25f * t;
        }
    }
}

// ---------------------------------------------------------------------------
// Kernel B (r5 math, 512-thread rebalanced schedule):
// conv3+tanh+pool (400 tasks, 1 round) -> c5 (4 thr/out) -> fc1 (2 thr/out)
// -> fc2 (4 thr/out).
__global__ __launch_bounds__(512) void lenet_back(
    const float* __restrict__ out2,  // [B,6,14,14]
    const float* __restrict__ c3_w,  // [16,6,5,5]
    const float* __restrict__ c3_b,  // [16]
    const float* __restrict__ c5_w,  // [120,16,5,5]
    const float* __restrict__ c5_b,  // [120]
    const float* __restrict__ l1_w,  // [84,120]
    const float* __restrict__ l1_b,  // [84]
    const float* __restrict__ l2_w,  // [10,84]
    const float* __restrict__ l2_b,  // [10]
    float* __restrict__ out)         // [B,10]
{
    __shared__ float a2[6 * 14 * 18];
    __shared__ float a3[400];
    __shared__ float f5[120];
    __shared__ float f6[84];

    const int b = blockIdx.x;
    const int tid = threadIdx.x;

    for (int i = tid; i < 1176; i += 512) {
        int row = i / 14, c = i % 14;
        a2[row * 18 + c] = out2[(size_t)b * 1176 + i];
    }
    __syncthreads();

    // conv3 + bias + tanh + pool: 400 tasks, one round (r5 body verbatim)
    if (tid < 400) {
        const int oc = tid / 25;
        const int rr = tid % 25;
        const int py = rr / 5, px = rr % 5;
        const int x0 = px * 2, y0 = py * 2;
        float a00 = 0.f, a01 = 0.f, a10 = 0.f, a11 = 0.f;
#pragma unroll 1
        for (int ic = 0; ic < 6; ic++) {
            const float* wr = c3_w + (oc * 6 + ic) * 25;
            float w[25];
#pragma unroll
            for (int q = 0; q < 25; q++) w[q] = wr[q];
#pragma unroll
            for (int t6 = 0; t6 < 6; t6++) {
                float seg[6];
                const float2* sp = (const float2*)&a2[(ic * 14 + y0 + t6) * 18 + x0];
#pragma unroll
                for (int q = 0; q < 3; q++) {
                    float2 v = sp[q];
                    seg[2 * q] = v.x; seg[2 * q + 1] = v.y;
                }
                if (t6 < 5) {
#pragma unroll
                    for (int kx = 0; kx < 5; kx++) {
                        float wv = w[t6 * 5 + kx];
                        a00 += wv * seg[kx]; a01 += wv * seg[kx + 1];
                    }
                }
                if (t6 >= 1) {
#pragma unroll
                    for (int kx = 0; kx < 5; kx++) {
                        float wv = w[(t6 - 1) * 5 + kx];
                        a10 += wv * seg[kx]; a11 += wv * seg[kx + 1];
                    }
                }
            }
        }
        const float bb = c3_b[oc];
        a3[tid] = 0.25f * (fast_tanh(a00 + bb) + fast_tanh(a01 + bb) +
                           fast_tanh(a10 + bb) + fast_tanh(a11 + bb));
    }
    __syncthreads();

    // c5: 120 outputs x 4 threads (100-elem partial dots, shfl-reduce over 4)
    if (tid < 480) {
        const int o = tid >> 2;
        const int part = tid & 3;
        float acc = 0.0f;
        const float4* wp = (const float4*)(c5_w + (size_t)o * 400) + part * 25;
        const float4* ap = ((const float4*)a3) + part * 25;
#pragma unroll 5
        for (int q = 0; q < 25; q++) {
            float4 wv = wp[q], av = ap[q];
            acc += wv.x * av.x + wv.y * av.y + wv.z * av.z + wv.w * av.w;
        }
        acc += __shfl_xor(acc, 1);
        acc += __shfl_xor(acc, 2);
        if (part == 0) f5[o] = fast_tanh(acc + c5_b[o]);
    }
    __syncthreads();

    // fc1: 84 outputs x 2 threads (60-elem halves)
    if (tid < 168) {
        const int o = tid >> 1;
        const int part = tid & 1;
        float acc = 0.0f;
        const float4* wp = (const float4*)(l1_w + o * 120) + part * 15;
        const float4* fp = ((const float4*)f5) + part * 15;
#pragma unroll
        for (int q = 0; q < 15; q++) {
            float4 wv = wp[q], fv = fp[q];
            acc += wv.x * fv.x + wv.y * fv.y + wv.z * fv.z + wv.w * fv.w;
        }
        acc += __shfl_xor(acc, 1);
        if (part == 0) f6[o] = fast_tanh(acc + l1_b[o]);
    }
    __syncthreads();

    // fc2: 10 outputs x 4 threads (21-elem quarters)
    if (tid < 40) {
        const int o = tid >> 2;
        const int part = tid & 3;
        float acc = 0.0f;
        const float* wp = l2_w + o * 84 + part * 21;
        const float* fp = f6 + part * 21;
#pragma unroll
        for (int q = 0; q < 21; q++) acc += wp[q] * fp[q];
        acc += __shfl_xor(acc, 1);
        acc += __shfl_xor(acc, 2);
        if (part == 0) out[(size_t)b * 10 + o] = acc + l2_b[o];
    }
}

extern "C" void kernel_launch(void* const* d_in, const int* in_sizes, int n_in,
                              void* d_out, int out_size, void* d_ws, size_t ws_size,
                              hipStream_t stream) {
    const float* x       = (const float*)d_in[0];
    const float* filters = (const float*)d_in[1];
    const float* c1_w    = (const float*)d_in[2];
    const float* c1_b    = (const float*)d_in[3];
    const float* c3_w    = (const float*)d_in[4];
    const float* c3_b    = (const float*)d_in[5];
    const float* c5_w    = (const float*)d_in[6];
    const float* c5_b    = (const float*)d_in[7];
    const float* l1_w    = (const float*)d_in[8];
    const float* l1_b    = (const float*)d_in[9];
    const float* l2_w    = (const float*)d_in[10];
    const float* l2_b    = (const float*)d_in[11];
    float* out = (float*)d_out;

    const int B = in_sizes[0] / 1024;

    // ws layout: [f0pk: 480 u32 @0, 2048 B][w1mf: 4096 u32 @2048, 16384 B][out2 @18432]
    unsigned int* f0pk = (unsigned int*)d_ws;
    unsigned int* w1mf = (unsigned int*)((char*)d_ws + 2048);
    float* out2 = (float*)((char*)d_ws + 18432);

    pack_weights<<<17, 256, 0, stream>>>(c1_w, filters, f0pk, w1mf);
    lenet_front<<<B, 512, 0, stream>>>(x, f0pk, w1mf, c1_b, out2);
    lenet_back<<<B, 512, 0, stream>>>(out2, c3_w, c3_b, c5_w, c5_b,
                                      l1_w, l1_b, l2_w, l2_b, out);
}

// Round 14
// 300.208 us; speedup vs baseline: 1.0517x; 1.0517x over previous
//
#include <hip/hip_runtime.h>
#include <hip/hip_bf16.h>
#include <cstddef>

typedef _Float16 h2 __attribute__((ext_vector_type(2)));
typedef _Float16 half8 __attribute__((ext_vector_type(8)));
typedef float f32x4 __attribute__((ext_vector_type(4)));

__device__ __forceinline__ float fast_tanh(float x) {
    float e = __expf(2.0f * x);
    return 1.0f - 2.0f / (e + 1.0f);
}

__device__ __forceinline__ float fdot2u(unsigned int a, unsigned int b, float c) {
    union U { unsigned int u; h2 h; };
    U ua; ua.u = a;
    U ub; ub.u = b;
    return __builtin_amdgcn_fdot2(ua.h, ub.h, c, false);
}

__device__ __forceinline__ unsigned int pkh(float a, float b) {
    union { _Float16 h; unsigned short u; } x, y;
    x.h = (_Float16)a; y.h = (_Float16)b;
    return ((unsigned int)y.u << 16) | (unsigned int)x.u;
}

// K-pair slot tables (round-7 HW-verified): p = 4*h + d. Each read
// instruction's 4 h-group bank bases (6*ty+tx mod 32) form {a,a+16,b,b+16}
// -> 2 lanes/bank (free). p0..14 real (ty 0..4, tx 0/2/4), p15 zero slot.
#define TY64 0x11B44891A440ULL      // 3 bits per p
#define TX64 0xF120120120120120ULL  // 4 bits per p, value = tx/2
#define XST 38                      // s1p row stride in dwords; 38 mod 32 = 6
#define S1SZ (512 * XST + 64)

__device__ __forceinline__ void slotf(int p, int& ty, int& tx) {
    ty = (int)((TY64 >> (3 * p)) & 7);
    tx = (int)((TX64 >> (4 * p)) & 15) * 2;
}

// ---------------------------------------------------------------------------
// pack: f0pk (conv0 dot2 pairs, r11 verbatim) + w1mf (conv1 MFMA A-frags,
// r7-verified slot-table map)
__global__ void pack_weights(const float* __restrict__ c1_w,
                             const float* __restrict__ filters,
                             unsigned int* __restrict__ f0pk,   // [16][5][6]
                             unsigned int* __restrict__ w1mf) { // [16ic][4h][16oc][4d]
    int t = blockIdx.x * blockDim.x + threadIdx.x;
    if (t < 80) {
        int oc = t / 5, ky = t % 5;
        const float* w = filters + oc * 25 + ky * 5;
        unsigned int* d = f0pk + oc * 30 + ky * 6;
        d[0] = pkh(w[0], w[1]); d[1] = pkh(w[2], w[3]); d[2] = pkh(w[4], 0.f);
        d[3] = pkh(0.f, w[0]); d[4] = pkh(w[1], w[2]); d[5] = pkh(w[3], w[4]);
    } else if (t >= 256 && t < 256 + 4096) {
        int g = t - 256;
        int d = g & 3, oc = (g >> 2) & 15, hh = (g >> 6) & 3, ic = g >> 8;
        int p = 4 * hh + d, ty, tx; slotf(p, ty, tx);
        float lo = 0.f, hi = 0.f;
        if (p != 15 && oc < 6) {
            const float* w = c1_w + (oc * 16 + ic) * 25 + ty * 5 + tx;
            lo = w[0]; hi = (tx < 4) ? w[1] : 0.f;
        }
        w1mf[g] = pkh(lo, hi);
    }
}

// ---------------------------------------------------------------------------
// Front: conv0 dot2 (r11 core) -> s1p stride-38 + oc*2 stagger (r7 layout);
// conv1 MFMA with r7 slot-table reads + bias + tanh + pool -> out2.
// LDS: s1p 78080 B + xs2 2736 B = 80816 B -> 2 blocks/CU, 16 waves/CU.
__global__ __launch_bounds__(512, 2) void lenet_front(
    const float* __restrict__ x,            // [B,1,32,32]
    const unsigned int* __restrict__ f0pk,
    const unsigned int* __restrict__ w1mf,
    const float* __restrict__ c1_b,         // [6]
    float* __restrict__ out2)               // [B,6,14,14]
{
    __shared__ unsigned int xs2[36 * 19];   // padded input, f16 pairs (r11)
    __shared__ unsigned int s1p[S1SZ];      // tanh(conv0): dword x = (px x, px x+1)

    const int b = blockIdx.x;
    const int tid = threadIdx.x;
    const float* xb = x + (size_t)b * 1024;

    for (int i = tid; i < 36 * 19; i += 512) xs2[i] = 0u;
    for (int i = tid; i < S1SZ; i += 512) s1p[i] = 0u;  // gaps/zero-slot reads
    __syncthreads();
    // P0 (r11 verbatim): one element per thread
    {
        int r = tid >> 4, c2 = tid & 15;
        const float2 v = *(const float2*)(xb + r * 32 + c2 * 2);
        xs2[(r + 2) * 19 + c2 + 1] = pkh(v.x, v.y);
    }
    __syncthreads();

    // ---- Phase A (r11 verbatim core; write base -> stride 38 + oc*2 stagger)
    {
        const int tt = tid & 255;
        const int y = tt >> 3;
        const int xg = tt & 7;
        const int x0 = xg * 4;
        const int x0h = xg * 2;
        const int oc0 = (tid >> 8) * 8;
        unsigned int win2[5][5];
#pragma unroll
        for (int i = 0; i < 5; i++) {
            const unsigned int* pr = &xs2[(y + i) * 19 + x0h];
#pragma unroll
            for (int q = 0; q < 5; q++) win2[i][q] = pr[q];
        }
#pragma unroll 1
        for (int oc = oc0; oc < oc0 + 8; oc++) {
            const unsigned int* fw = f0pk + oc * 30;  // uniform -> s_load
            float a0 = 0.f, a1 = 0.f, a2 = 0.f, a3 = 0.f, a4 = 0.f;
#pragma unroll
            for (int ky = 0; ky < 5; ky++) {
                unsigned int w01 = fw[ky * 6 + 0], w23 = fw[ky * 6 + 1], w4z = fw[ky * 6 + 2];
                unsigned int zw0 = fw[ky * 6 + 3], w12 = fw[ky * 6 + 4], w34 = fw[ky * 6 + 5];
                a0 = fdot2u(w01, win2[ky][0], a0);
                a0 = fdot2u(w23, win2[ky][1], a0);
                a0 = fdot2u(w4z, win2[ky][2], a0);
                a1 = fdot2u(zw0, win2[ky][0], a1);
                a1 = fdot2u(w12, win2[ky][1], a1);
                a1 = fdot2u(w34, win2[ky][2], a1);
                a2 = fdot2u(w01, win2[ky][1], a2);
                a2 = fdot2u(w23, win2[ky][2], a2);
                a2 = fdot2u(w4z, win2[ky][3], a2);
                a3 = fdot2u(zw0, win2[ky][1], a3);
                a3 = fdot2u(w12, win2[ky][2], a3);
                a3 = fdot2u(w34, win2[ky][3], a3);
                a4 = fdot2u(w01, win2[ky][2], a4);
                a4 = fdot2u(w23, win2[ky][3], a4);
                a4 = fdot2u(w4z, win2[ky][4], a4);
            }
            float t0 = fast_tanh(a0), t1 = fast_tanh(a1), t2 = fast_tanh(a2);
            float t3 = fast_tanh(a3), t4 = fast_tanh(a4);
            int base = (oc * 32 + y) * XST + oc * 2 + x0;
            s1p[base + 0] = pkh(t0, t1);
            s1p[base + 1] = pkh(t1, t2);
            s1p[base + 2] = pkh(t2, t3);
            s1p[base + 3] = pkh(t3, t4);
        }
    }
    __syncthreads();

    // ---- Phase B (r7 P2 verbatim, 8-wave schedule): conv1 MFMA + epilogue
    const int lane = tid & 63;
    const int wid = tid >> 6;        // 0..7
    const int h = lane >> 4;
    const int c = lane & 15;

    half8 af[16];
#pragma unroll
    for (int ks = 0; ks < 16; ks++)
        af[ks] = *(const half8*)(w1mf + ((ks * 4 + h) * 16 + c) * 4);

    int offd[4];
#pragma unroll
    for (int d = 0; d < 4; ++d) {
        int p = 4 * h + d, ty, tx; slotf(p, ty, tx);
        offd[d] = ty * XST + tx + c;
    }

    float bias_l[4];
#pragma unroll
    for (int r = 0; r < 4; r++) {
        int rr = 4 * h + r;
        bias_l[r] = c1_b[rr < 6 ? rr : 5];
    }

#pragma unroll 1
    for (int q = wid; q < 28; q += 8) {
        const int py = q >> 1;
        const int xh = q & 1;
        const int x0 = 12 * xh;
        const int yy = 2 * py;

        f32x4 acc0 = {0.f, 0.f, 0.f, 0.f};
        f32x4 acc1 = {0.f, 0.f, 0.f, 0.f};
#pragma unroll
        for (int ks = 0; ks < 16; ks++) {
            const int kb = (ks * 32 + yy) * XST + ks * 2 + x0;
            union H8 { unsigned int u[4]; half8 hv; };
            H8 B0, B1;
#pragma unroll
            for (int d = 0; d < 4; ++d) {
                B0.u[d] = s1p[kb + offd[d]];
                B1.u[d] = s1p[kb + XST + offd[d]];
            }
            acc0 = __builtin_amdgcn_mfma_f32_16x16x32_f16(af[ks], B0.hv, acc0, 0, 0, 0);
            acc1 = __builtin_amdgcn_mfma_f32_16x16x32_f16(af[ks], B1.hv, acc1, 0, 0, 0);
        }
#pragma unroll
        for (int r = 0; r < 4; r++) {
            int rr = 4 * h + r;
            float t = fast_tanh(acc0[r] + bias_l[r]) + fast_tanh(acc1[r] + bias_l[r]);
            t += __shfl_xor(t, 1);
            int pq = (c >> 1) + 6 * xh;
            bool ok = (rr < 6) && ((c & 1) == 0) && (xh ? (pq >= 7) : (pq <= 6));
            if (ok) out2[((size_t)b * 6 + rr) * 196 + py * 14 + pq] = 0.25f * t;
        }
    }
}

// ---------------------------------------------------------------------------
// Back (r5/r11 verbatim, 256 threads): conv3+tanh+pool -> c5 -> fc1 -> fc2
__global__ __launch_bounds__(256) void lenet_back(
    const float* __restrict__ out2,
    const float* __restrict__ c3_w, const float* __restrict__ c3_b,
    const float* __restrict__ c5_w, const float* __restrict__ c5_b,
    const float* __restrict__ l1_w, const float* __restrict__ l1_b,
    const float* __restrict__ l2_w, const float* __restrict__ l2_b,
    float* __restrict__ out)
{
    __shared__ float a2[6 * 14 * 18];
    __shared__ float a3[400];
    __shared__ float f5[120];
    __shared__ float f6[84];

    const int b = blockIdx.x;
    const int tid = threadIdx.x;

    for (int i = tid; i < 1176; i += 256) {
        int row = i / 14, c = i % 14;
        a2[row * 18 + c] = out2[(size_t)b * 1176 + i];
    }
    __syncthreads();

    for (int t = tid; t < 400; t += 256) {
        const int oc = t / 25;
        const int rr = t % 25;
        const int py = rr / 5, px = rr % 5;
        const int x0 = px * 2, y0 = py * 2;
        float a00 = 0.f, a01 = 0.f, a10 = 0.f, a11 = 0.f;
#pragma unroll 1
        for (int ic = 0; ic < 6; ic++) {
            const float* wr = c3_w + (oc * 6 + ic) * 25;
            float w[25];
#pragma unroll
            for (int q = 0; q < 25; q++) w[q] = wr[q];
#pragma unroll
            for (int t6 = 0; t6 < 6; t6++) {
                float seg[6];
                const float2* sp = (const float2*)&a2[(ic * 14 + y0 + t6) * 18 + x0];
#pragma unroll
                for (int q = 0; q < 3; q++) {
                    float2 v = sp[q];
                    seg[2 * q] = v.x; seg[2 * q + 1] = v.y;
                }
                if (t6 < 5) {
#pragma unroll
                    for (int kx = 0; kx < 5; kx++) {
                        float wv = w[t6 * 5 + kx];
                        a00 += wv * seg[kx]; a01 += wv * seg[kx + 1];
                    }
                }
                if (t6 >= 1) {
#pragma unroll
                    for (int kx = 0; kx < 5; kx++) {
                        float wv = w[(t6 - 1) * 5 + kx];
                        a10 += wv * seg[kx]; a11 += wv * seg[kx + 1];
                    }
                }
            }
        }
        const float bb = c3_b[oc];
        a3[t] = 0.25f * (fast_tanh(a00 + bb) + fast_tanh(a01 + bb) +
                         fast_tanh(a10 + bb) + fast_tanh(a11 + bb));
    }
    __syncthreads();

    if (tid < 240) {
        const int o = tid >> 1;
        const int part = tid & 1;
        float acc = 0.0f;
        const float4* wp = (const float4*)(c5_w + (size_t)o * 400) + part * 50;
        const float4* ap = ((const float4*)a3) + part * 50;
#pragma unroll 5
        for (int q = 0; q < 50; q++) {
            float4 wv = wp[q], av = ap[q];
            acc += wv.x * av.x + wv.y * av.y + wv.z * av.z + wv.w * av.w;
        }
        acc += __shfl_xor(acc, 1);
        if (part == 0) f5[o] = fast_tanh(acc + c5_b[o]);
    }
    __syncthreads();

    if (tid < 84) {
        float acc = l1_b[tid];
        const float4* wp = (const float4*)(l1_w + tid * 120);
        const float4* fp = (const float4*)f5;
#pragma unroll
        for (int q = 0; q < 30; q++) {
            float4 wv = wp[q], fv = fp[q];
            acc += wv.x * fv.x + wv.y * fv.y + wv.z * fv.z + wv.w * fv.w;
        }
        f6[tid] = fast_tanh(acc);
    }
    __syncthreads();

    if (tid < 10) {
        float acc = l2_b[tid];
        const float* wp = l2_w + tid * 84;
#pragma unroll
        for (int q = 0; q < 84; q++) acc += wp[q] * f6[q];
        out[(size_t)b * 10 + tid] = acc;
    }
}

extern "C" void kernel_launch(void* const* d_in, const int* in_sizes, int n_in,
                              void* d_out, int out_size, void* d_ws, size_t ws_size,
                              hipStream_t stream) {
    const float* x       = (const float*)d_in[0];
    const float* filters = (const float*)d_in[1];
    const float* c1_w    = (const float*)d_in[2];
    const float* c1_b    = (const float*)d_in[3];
    const float* c3_w    = (const float*)d_in[4];
    const float* c3_b    = (const float*)d_in[5];
    const float* c5_w    = (const float*)d_in[6];
    const float* c5_b    = (const float*)d_in[7];
    const float* l1_w    = (const float*)d_in[8];
    const float* l1_b    = (const float*)d_in[9];
    const float* l2_w    = (const float*)d_in[10];
    const float* l2_b    = (const float*)d_in[11];
    float* out = (float*)d_out;

    const int B = in_sizes[0] / 1024;

    // ws layout: [f0pk: 480 u32 @0, 2048 B][w1mf: 4096 u32 @2048, 16384 B][out2 @18432]
    unsigned int* f0pk = (unsigned int*)d_ws;
    unsigned int* w1mf = (unsigned int*)((char*)d_ws + 2048);
    float* out2 = (float*)((char*)d_ws + 18432);

    pack_weights<<<17, 256, 0, stream>>>(c1_w, filters, f0pk, w1mf);
    lenet_front<<<B, 512, 0, stream>>>(x, f0pk, w1mf, c1_b, out2);
    lenet_back<<<B, 256, 0, stream>>>(out2, c3_w, c3_b, c5_w, c5_b,
                                      l1_w, l1_b, l2_w, l2_b, out);
}

// Round 15
// 292.443 us; speedup vs baseline: 1.0796x; 1.0266x over previous
//
#include <hip/hip_runtime.h>
#include <hip/hip_bf16.h>
#include <cstddef>

typedef _Float16 h2 __attribute__((ext_vector_type(2)));
typedef _Float16 half8 __attribute__((ext_vector_type(8)));
typedef float f32x4 __attribute__((ext_vector_type(4)));

__device__ __forceinline__ float fast_tanh(float x) {
    float e = __expf(2.0f * x);
    return 1.0f - 2.0f / (e + 1.0f);
}

__device__ __forceinline__ float fdot2u(unsigned int a, unsigned int b, float c) {
    union U { unsigned int u; h2 h; };
    U ua; ua.u = a;
    U ub; ub.u = b;
    return __builtin_amdgcn_fdot2(ua.h, ub.h, c, false);
}

__device__ __forceinline__ unsigned int pkh(float a, float b) {
    union { _Float16 h; unsigned short u; } x, y;
    x.h = (_Float16)a; y.h = (_Float16)b;
    return ((unsigned int)y.u << 16) | (unsigned int)x.u;
}

// K-pair slot tables (round-7 HW-verified): p = 4*h + d. Each read
// instruction's 4 h-group bank bases (6*ty+tx mod 32) form {a,a+16,b,b+16}
// -> 2 lanes/bank (free). p0..14 real (ty 0..4, tx 0/2/4), p15 zero slot.
#define TY64 0x11B44891A440ULL      // 3 bits per p
#define TX64 0xF120120120120120ULL  // 4 bits per p, value = tx/2
#define XST 38                      // s1p row stride in dwords; 38 mod 32 = 6
#define S1SZ (512 * XST + 64)

__device__ __forceinline__ void slotf(int p, int& ty, int& tx) {
    ty = (int)((TY64 >> (3 * p)) & 7);
    tx = (int)((TX64 >> (4 * p)) & 15) * 2;
}

// ---------------------------------------------------------------------------
// pack: f0pk (conv0 dot2 pairs) + w1mf (conv1 MFMA A-frags, r7 slot-table map)
__global__ void pack_weights(const float* __restrict__ c1_w,
                             const float* __restrict__ filters,
                             unsigned int* __restrict__ f0pk,   // [16][5][6]
                             unsigned int* __restrict__ w1mf) { // [16ic][4h][16oc][4d]
    int t = blockIdx.x * blockDim.x + threadIdx.x;
    if (t < 80) {
        int oc = t / 5, ky = t % 5;
        const float* w = filters + oc * 25 + ky * 5;
        unsigned int* d = f0pk + oc * 30 + ky * 6;
        d[0] = pkh(w[0], w[1]); d[1] = pkh(w[2], w[3]); d[2] = pkh(w[4], 0.f);
        d[3] = pkh(0.f, w[0]); d[4] = pkh(w[1], w[2]); d[5] = pkh(w[3], w[4]);
    } else if (t >= 256 && t < 256 + 4096) {
        int g = t - 256;
        int d = g & 3, oc = (g >> 2) & 15, hh = (g >> 6) & 3, ic = g >> 8;
        int p = 4 * hh + d, ty, tx; slotf(p, ty, tx);
        float lo = 0.f, hi = 0.f;
        if (p != 15 && oc < 6) {
            const float* w = c1_w + (oc * 16 + ic) * 25 + ty * 5 + tx;
            lo = w[0]; hi = (tx < 4) ? w[1] : 0.f;
        }
        w1mf[g] = pkh(lo, hi);
    }
}

// ---------------------------------------------------------------------------
// Front (r14 + a4-trim + setprio): conv0 dot2 -> s1p stride-38/oc*2-stagger;
// conv1 MFMA slot-table reads + bias + tanh + pool -> out2.
// LDS: s1p 78080 B + xs2 2736 B = 80816 B -> 2 blocks/CU, 16 waves/CU.
__global__ __launch_bounds__(512, 2) void lenet_front(
    const float* __restrict__ x,            // [B,1,32,32]
    const unsigned int* __restrict__ f0pk,
    const unsigned int* __restrict__ w1mf,
    const float* __restrict__ c1_b,         // [6]
    float* __restrict__ out2)               // [B,6,14,14]
{
    __shared__ unsigned int xs2[36 * 19];   // padded input, f16 pairs (r11)
    __shared__ unsigned int s1p[S1SZ];      // tanh(conv0): dword x = (px x, px x+1)

    const int b = blockIdx.x;
    const int tid = threadIdx.x;
    const int lane = tid & 63;
    const float* xb = x + (size_t)b * 1024;

    for (int i = tid; i < 36 * 19; i += 512) xs2[i] = 0u;
    for (int i = tid; i < S1SZ; i += 512) s1p[i] = 0u;  // gaps/zero-slot reads
    __syncthreads();
    // P0 (r11 verbatim): one element per thread
    {
        int r = tid >> 4, c2 = tid & 15;
        const float2 v = *(const float2*)(xb + r * 32 + c2 * 2);
        xs2[(r + 2) * 19 + c2 + 1] = pkh(v.x, v.y);
    }
    __syncthreads();

    // ---- Phase A (r14 core, a4 replaced by neighbor-shfl of t0):
    // t4(thread xg) == t0(thread xg+1) bit-identically; xg=7 lanes produce
    // garbage t4 consumed only by zero-weight slots (finite tanh values).
    {
        const int tt = tid & 255;
        const int y = tt >> 3;
        const int xg = tt & 7;
        const int x0 = xg * 4;
        const int x0h = xg * 2;
        const int oc0 = (tid >> 8) * 8;
        unsigned int win2[5][4];
#pragma unroll
        for (int i = 0; i < 5; i++) {
            const unsigned int* pr = &xs2[(y + i) * 19 + x0h];
#pragma unroll
            for (int q = 0; q < 4; q++) win2[i][q] = pr[q];
        }
#pragma unroll 1
        for (int oc = oc0; oc < oc0 + 8; oc++) {
            const unsigned int* fw = f0pk + oc * 30;  // uniform -> s_load
            float a0 = 0.f, a1 = 0.f, a2 = 0.f, a3 = 0.f;
#pragma unroll
            for (int ky = 0; ky < 5; ky++) {
                unsigned int w01 = fw[ky * 6 + 0], w23 = fw[ky * 6 + 1], w4z = fw[ky * 6 + 2];
                unsigned int zw0 = fw[ky * 6 + 3], w12 = fw[ky * 6 + 4], w34 = fw[ky * 6 + 5];
                a0 = fdot2u(w01, win2[ky][0], a0);
                a0 = fdot2u(w23, win2[ky][1], a0);
                a0 = fdot2u(w4z, win2[ky][2], a0);
                a1 = fdot2u(zw0, win2[ky][0], a1);
                a1 = fdot2u(w12, win2[ky][1], a1);
                a1 = fdot2u(w34, win2[ky][2], a1);
                a2 = fdot2u(w01, win2[ky][1], a2);
                a2 = fdot2u(w23, win2[ky][2], a2);
                a2 = fdot2u(w4z, win2[ky][3], a2);
                a3 = fdot2u(zw0, win2[ky][1], a3);
                a3 = fdot2u(w12, win2[ky][2], a3);
                a3 = fdot2u(w34, win2[ky][3], a3);
            }
            float t0 = fast_tanh(a0), t1 = fast_tanh(a1);
            float t2 = fast_tanh(a2), t3 = fast_tanh(a3);
            float t4 = __shfl(t0, lane + 1);   // next thread's t0 (xg<7 real)
            int base = (oc * 32 + y) * XST + oc * 2 + x0;
            s1p[base + 0] = pkh(t0, t1);
            s1p[base + 1] = pkh(t1, t2);
            s1p[base + 2] = pkh(t2, t3);
            s1p[base + 3] = pkh(t3, t4);
        }
    }
    __syncthreads();

    // ---- Phase B (r14 verbatim + setprio around MFMA loop)
    const int wid = tid >> 6;        // 0..7
    const int h = lane >> 4;
    const int c = lane & 15;

    half8 af[16];
#pragma unroll
    for (int ks = 0; ks < 16; ks++)
        af[ks] = *(const half8*)(w1mf + ((ks * 4 + h) * 16 + c) * 4);

    int offd[4];
#pragma unroll
    for (int d = 0; d < 4; ++d) {
        int p = 4 * h + d, ty, tx; slotf(p, ty, tx);
        offd[d] = ty * XST + tx + c;
    }

    float bias_l[4];
#pragma unroll
    for (int r = 0; r < 4; r++) {
        int rr = 4 * h + r;
        bias_l[r] = c1_b[rr < 6 ? rr : 5];
    }

#pragma unroll 1
    for (int q = wid; q < 28; q += 8) {
        const int py = q >> 1;
        const int xh = q & 1;
        const int x0 = 12 * xh;
        const int yy = 2 * py;

        f32x4 acc0 = {0.f, 0.f, 0.f, 0.f};
        f32x4 acc1 = {0.f, 0.f, 0.f, 0.f};
        __builtin_amdgcn_s_setprio(1);
#pragma unroll
        for (int ks = 0; ks < 16; ks++) {
            const int kb = (ks * 32 + yy) * XST + ks * 2 + x0;
            union H8 { unsigned int u[4]; half8 hv; };
            H8 B0, B1;
#pragma unroll
            for (int d = 0; d < 4; ++d) {
                B0.u[d] = s1p[kb + offd[d]];
                B1.u[d] = s1p[kb + XST + offd[d]];
            }
            acc0 = __builtin_amdgcn_mfma_f32_16x16x32_f16(af[ks], B0.hv, acc0, 0, 0, 0);
            acc1 = __builtin_amdgcn_mfma_f32_16x16x32_f16(af[ks], B1.hv, acc1, 0, 0, 0);
        }
        __builtin_amdgcn_s_setprio(0);
#pragma unroll
        for (int r = 0; r < 4; r++) {
            int rr = 4 * h + r;
            float t = fast_tanh(acc0[r] + bias_l[r]) + fast_tanh(acc1[r] + bias_l[r]);
            t += __shfl_xor(t, 1);
            int pq = (c >> 1) + 6 * xh;
            bool ok = (rr < 6) && ((c & 1) == 0) && (xh ? (pq >= 7) : (pq <= 6));
            if (ok) out2[((size_t)b * 6 + rr) * 196 + py * 14 + pq] = 0.25f * t;
        }
    }
}

// ---------------------------------------------------------------------------
// Back (r5/r11 verbatim, 256 threads): conv3+tanh+pool -> c5 -> fc1 -> fc2
__global__ __launch_bounds__(256) void lenet_back(
    const float* __restrict__ out2,
    const float* __restrict__ c3_w, const float* __restrict__ c3_b,
    const float* __restrict__ c5_w, const float* __restrict__ c5_b,
    const float* __restrict__ l1_w, const float* __restrict__ l1_b,
    const float* __restrict__ l2_w, const float* __restrict__ l2_b,
    float* __restrict__ out)
{
    __shared__ float a2[6 * 14 * 18];
    __shared__ float a3[400];
    __shared__ float f5[120];
    __shared__ float f6[84];

    const int b = blockIdx.x;
    const int tid = threadIdx.x;

    for (int i = tid; i < 1176; i += 256) {
        int row = i / 14, c = i % 14;
        a2[row * 18 + c] = out2[(size_t)b * 1176 + i];
    }
    __syncthreads();

    for (int t = tid; t < 400; t += 256) {
        const int oc = t / 25;
        const int rr = t % 25;
        const int py = rr / 5, px = rr % 5;
        const int x0 = px * 2, y0 = py * 2;
        float a00 = 0.f, a01 = 0.f, a10 = 0.f, a11 = 0.f;
#pragma unroll 1
        for (int ic = 0; ic < 6; ic++) {
            const float* wr = c3_w + (oc * 6 + ic) * 25;
            float w[25];
#pragma unroll
            for (int q = 0; q < 25; q++) w[q] = wr[q];
#pragma unroll
            for (int t6 = 0; t6 < 6; t6++) {
                float seg[6];
                const float2* sp = (const float2*)&a2[(ic * 14 + y0 + t6) * 18 + x0];
#pragma unroll
                for (int q = 0; q < 3; q++) {
                    float2 v = sp[q];
                    seg[2 * q] = v.x; seg[2 * q + 1] = v.y;
                }
                if (t6 < 5) {
#pragma unroll
                    for (int kx = 0; kx < 5; kx++) {
                        float wv = w[t6 * 5 + kx];
                        a00 += wv * seg[kx]; a01 += wv * seg[kx + 1];
                    }
                }
                if (t6 >= 1) {
#pragma unroll
                    for (int kx = 0; kx < 5; kx++) {
                        float wv = w[(t6 - 1) * 5 + kx];
                        a10 += wv * seg[kx]; a11 += wv * seg[kx + 1];
                    }
                }
            }
        }
        const float bb = c3_b[oc];
        a3[t] = 0.25f * (fast_tanh(a00 + bb) + fast_tanh(a01 + bb) +
                         fast_tanh(a10 + bb) + fast_tanh(a11 + bb));
    }
    __syncthreads();

    if (tid < 240) {
        const int o = tid >> 1;
        const int part = tid & 1;
        float acc = 0.0f;
        const float4* wp = (const float4*)(c5_w + (size_t)o * 400) + part * 50;
        const float4* ap = ((const float4*)a3) + part * 50;
#pragma unroll 5
        for (int q = 0; q < 50; q++) {
            float4 wv = wp[q], av = ap[q];
            acc += wv.x * av.x + wv.y * av.y + wv.z * av.z + wv.w * av.w;
        }
        acc += __shfl_xor(acc, 1);
        if (part == 0) f5[o] = fast_tanh(acc + c5_b[o]);
    }
    __syncthreads();

    if (tid < 84) {
        float acc = l1_b[tid];
        const float4* wp = (const float4*)(l1_w + tid * 120);
        const float4* fp = (const float4*)f5;
#pragma unroll
        for (int q = 0; q < 30; q++) {
            float4 wv = wp[q], fv = fp[q];
            acc += wv.x * fv.x + wv.y * fv.y + wv.z * fv.z + wv.w * fv.w;
        }
        f6[tid] = fast_tanh(acc);
    }
    __syncthreads();

    if (tid < 10) {
        float acc = l2_b[tid];
        const float* wp = l2_w + tid * 84;
#pragma unroll
        for (int q = 0; q < 84; q++) acc += wp[q] * f6[q];
        out[(size_t)b * 10 + tid] = acc;
    }
}

extern "C" void kernel_launch(void* const* d_in, const int* in_sizes, int n_in,
                              void* d_out, int out_size, void* d_ws, size_t ws_size,
                              hipStream_t stream) {
    const float* x       = (const float*)d_in[0];
    const float* filters = (const float*)d_in[1];
    const float* c1_w    = (const float*)d_in[2];
    const float* c1_b    = (const float*)d_in[3];
    const float* c3_w    = (const float*)d_in[4];
    const float* c3_b    = (const float*)d_in[5];
    const float* c5_w    = (const float*)d_in[6];
    const float* c5_b    = (const float*)d_in[7];
    const float* l1_w    = (const float*)d_in[8];
    const float* l1_b    = (const float*)d_in[9];
    const float* l2_w    = (const float*)d_in[10];
    const float* l2_b    = (const float*)d_in[11];
    float* out = (float*)d_out;

    const int B = in_sizes[0] / 1024;

    // ws layout: [f0pk: 480 u32 @0, 2048 B][w1mf: 4096 u32 @2048, 16384 B][out2 @18432]
    unsigned int* f0pk = (unsigned int*)d_ws;
    unsigned int* w1mf = (unsigned int*)((char*)d_ws + 2048);
    float* out2 = (float*)((char*)d_ws + 18432);

    pack_weights<<<17, 256, 0, stream>>>(c1_w, filters, f0pk, w1mf);
    lenet_front<<<B, 512, 0, stream>>>(x, f0pk, w1mf, c1_b, out2);
    lenet_back<<<B, 256, 0, stream>>>(out2, c3_w, c3_b, c5_w, c5_b,
                                      l1_w, l1_b, l2_w, l2_b, out);
}

// Round 16
// 256.710 us; speedup vs baseline: 1.2299x; 1.1392x over previous
//
#include <hip/hip_runtime.h>
#include <hip/hip_bf16.h>
#include <cstddef>

typedef _Float16 half8 __attribute__((ext_vector_type(8)));
typedef float f32x4 __attribute__((ext_vector_type(4)));
typedef __fp16 fp16x2 __attribute__((ext_vector_type(2)));

__device__ __forceinline__ float fast_tanh(float x) {
    float e = __expf(2.0f * x);
    return 1.0f - 2.0f / (e + 1.0f);
}
__device__ __forceinline__ unsigned int pkrtz(float a, float b) {
    fp16x2 r = __builtin_amdgcn_cvt_pkrtz(a, b);
    union { fp16x2 h; unsigned int u; } v; v.h = r; return v.u;
}
__device__ __forceinline__ unsigned int pkh(float a, float b) {
    union { _Float16 h; unsigned short u; } x, y;
    x.h = (_Float16)a; y.h = (_Float16)b;
    return ((unsigned int)y.u << 16) | (unsigned int)x.u;
}

// K-pair slot tables (round-7 HW-verified): p = 4*h + d. Each read
// instruction's 4 h-group bank bases (6*ty+tx mod 32) form {a,a+16,b,b+16}
// -> 2 lanes/bank (free). p0..14 real (ty 0..4, tx 0/2/4), p15 zero slot.
#define TY64 0x11B44891A440ULL      // 3 bits per p
#define TX64 0xF120120120120120ULL  // 4 bits per p, value = tx/2
#define XST 38                      // s1p row stride in dwords; 38 mod 32 = 6
#define S1SZ 19488                  // max write/read 19479; 2 blocks/CU fits

__device__ __forceinline__ void slotf(int p, int& ty, int& tx) {
    ty = (int)((TY64 >> (3 * p)) & 7);
    tx = (int)((TX64 >> (4 * p)) & 15) * 2;
}

// ---------------------------------------------------------------------------
// pack (r7 verbatim): w0mf = conv0 A-frags, w1mf = conv1 A-frags (slot map)
__global__ void pack_weights(const float* __restrict__ c1_w,
                             const float* __restrict__ filters,
                             unsigned int* __restrict__ w0mf,   // [4h][16oc][4d]
                             unsigned int* __restrict__ w1mf) { // [16ic][4h][16oc][4d]
    int t = blockIdx.x * blockDim.x + threadIdx.x;
    if (t < 256) {
        int d = t & 3, oc = (t >> 2) & 15, hh = (t >> 6) & 3;
        int p = 4 * hh + d, ty, tx; slotf(p, ty, tx);
        float lo = 0.f, hi = 0.f;
        if (p != 15) {
            const float* w = filters + oc * 25 + ty * 5 + tx;
            lo = w[0]; hi = (tx < 4) ? w[1] : 0.f;
        }
        w0mf[t] = pkh(lo, hi);
    } else if (t < 256 + 4096) {
        int g = t - 256;
        int d = g & 3, oc = (g >> 2) & 15, hh = (g >> 6) & 3, ic = g >> 8;
        int p = 4 * hh + d, ty, tx; slotf(p, ty, tx);
        float lo = 0.f, hi = 0.f;
        if (p != 15 && oc < 6) {
            const float* w = c1_w + (oc * 16 + ic) * 25 + ty * 5 + tx;
            lo = w[0]; hi = (tx < 4) ? w[1] : 0.f;
        }
        w1mf[g] = pkh(lo, hi);
    }
}

// ---------------------------------------------------------------------------
// Front (r7 P0+P1+P2 verbatim, aliased staging): input pair-dup staged in
// s1p[0..1367] -> conv0 MFMA into regs -> barrier -> tanh epilogue writes
// s1p (stride 38, ch*2 stagger) -> conv1 MFMA + bias + tanh + pool -> out2.
// LDS: 77952 B -> 2 blocks/CU, 16 waves/CU.
__global__ __launch_bounds__(512, 2) void lenet_front(
    const float* __restrict__ x,            // [B,1,32,32]
    const unsigned int* __restrict__ w0mf,
    const unsigned int* __restrict__ w1mf,
    const float* __restrict__ c1_b,         // [6]
    float* __restrict__ out2)               // [B,6,14,14]
{
    __shared__ unsigned int s1p[S1SZ];  // dwords 0..1367 double as input staging

    const int b = blockIdx.x;
    const int tid = threadIdx.x;
    const int lane = tid & 63;
    const int wid = tid >> 6;        // 0..7
    const int h = (lane >> 4) & 3;
    const int c = lane & 15;
    const float* xb = x + (size_t)b * 1024;

    for (int i = tid; i < S1SZ; i += 512) s1p[i] = 0u;

    // shared slot-table read offsets (P1 conv0 + P2 conv1)
    int offd[4];
#pragma unroll
    for (int d = 0; d < 4; ++d) {
        int p = 4 * h + d, ty, tx; slotf(p, ty, tx);
        offd[d] = ty * XST + tx + c;
    }
    half8 af0 = *(const half8*)(w0mf + (h * 16 + c) * 4);
    __syncthreads();

    // ---- P0 (r7 verbatim, into alias region): input -> pair-dup f16 rows
    {
        int r = tid >> 4, cc = tid & 15;
        float2 v = *(const float2*)(xb + r * 32 + cc * 2);
        float vnext = __shfl(v.x, lane + 1);
        if (cc == 15) vnext = 0.f;
        unsigned int d0 = pkrtz(v.x, v.y);
        unsigned int d1 = pkrtz(v.y, vnext);
        unsigned int* row = &s1p[(r + 2) * XST];
        *(uint2*)&row[2 * cc + 2] = make_uint2(d0, d1);
        if (cc == 0) row[1] = pkrtz(0.f, v.x);
    }
    __syncthreads();

    union H8 { unsigned int u[4]; half8 hv; };

    // ---- P1a: conv0 MFMA, all inputs consumed into accumulator regs
    f32x4 AC0[4], AC1[4];
#pragma unroll
    for (int yi = 0; yi < 4; ++yi) {
        const int y = 4 * wid + yi;
        const int base = y * XST;
        H8 B0, B1;
#pragma unroll
        for (int d = 0; d < 4; ++d) {
            B0.u[d] = s1p[base + offd[d]];
            B1.u[d] = s1p[base + 16 + offd[d]];
        }
        f32x4 z = {0.f, 0.f, 0.f, 0.f};
        AC0[yi] = __builtin_amdgcn_mfma_f32_16x16x32_f16(af0, B0.hv, z, 0, 0, 0);
        AC1[yi] = __builtin_amdgcn_mfma_f32_16x16x32_f16(af0, B1.hv, z, 0, 0, 0);
    }
    __syncthreads();   // all staging reads done -> safe to overwrite alias

    // ---- P1b (r7 epilogue verbatim): tanh + pair-dup writes, ch*2 stagger
#pragma unroll
    for (int yi = 0; yi < 4; ++yi) {
        const int y = 4 * wid + yi;
#pragma unroll
        for (int r = 0; r < 4; ++r) {
            int ch = 4 * h + r;
            float t0 = fast_tanh(AC0[yi][r]), t1 = fast_tanh(AC1[yi][r]);
            float t0n = __shfl(t0, lane + 1);
            float t1n = __shfl(t1, lane + 1);
            float tb  = __shfl(t1, lane & 48);
            float n0 = (c < 15) ? t0n : tb;
            float n1 = (c < 15) ? t1n : 0.f;
            int rb = (ch * 32 + y) * XST + ch * 2;
            s1p[rb + c]      = pkrtz(t0, n0);
            s1p[rb + 16 + c] = pkrtz(t1, n1);
        }
    }
    __syncthreads();

    // ---- P2 (r15 verbatim): conv1 MFMA slot-table reads + setprio + epilogue
    half8 af[16];
#pragma unroll
    for (int ks = 0; ks < 16; ks++)
        af[ks] = *(const half8*)(w1mf + ((ks * 4 + h) * 16 + c) * 4);

    float bias_l[4];
#pragma unroll
    for (int r = 0; r < 4; r++) {
        int rr = 4 * h + r;
        bias_l[r] = c1_b[rr < 6 ? rr : 5];
    }

#pragma unroll 1
    for (int q = wid; q < 28; q += 8) {
        const int py = q >> 1;
        const int xh = q & 1;
        const int x0 = 12 * xh;
        const int yy = 2 * py;

        f32x4 acc0 = {0.f, 0.f, 0.f, 0.f};
        f32x4 acc1 = {0.f, 0.f, 0.f, 0.f};
        __builtin_amdgcn_s_setprio(1);
#pragma unroll
        for (int ks = 0; ks < 16; ks++) {
            const int kb = (ks * 32 + yy) * XST + ks * 2 + x0;
            H8 B0, B1;
#pragma unroll
            for (int d = 0; d < 4; ++d) {
                B0.u[d] = s1p[kb + offd[d]];
                B1.u[d] = s1p[kb + XST + offd[d]];
            }
            acc0 = __builtin_amdgcn_mfma_f32_16x16x32_f16(af[ks], B0.hv, acc0, 0, 0, 0);
            acc1 = __builtin_amdgcn_mfma_f32_16x16x32_f16(af[ks], B1.hv, acc1, 0, 0, 0);
        }
        __builtin_amdgcn_s_setprio(0);
#pragma unroll
        for (int r = 0; r < 4; r++) {
            int rr = 4 * h + r;
            float t = fast_tanh(acc0[r] + bias_l[r]) + fast_tanh(acc1[r] + bias_l[r]);
            t += __shfl_xor(t, 1);
            int pq = (c >> 1) + 6 * xh;
            bool ok = (rr < 6) && ((c & 1) == 0) && (xh ? (pq >= 7) : (pq <= 6));
            if (ok) out2[((size_t)b * 6 + rr) * 196 + py * 14 + pq] = 0.25f * t;
        }
    }
}

// ---------------------------------------------------------------------------
// Back (r5/r11 verbatim, 256 threads): conv3+tanh+pool -> c5 -> fc1 -> fc2
__global__ __launch_bounds__(256) void lenet_back(
    const float* __restrict__ out2,
    const float* __restrict__ c3_w, const float* __restrict__ c3_b,
    const float* __restrict__ c5_w, const float* __restrict__ c5_b,
    const float* __restrict__ l1_w, const float* __restrict__ l1_b,
    const float* __restrict__ l2_w, const float* __restrict__ l2_b,
    float* __restrict__ out)
{
    __shared__ float a2[6 * 14 * 18];
    __shared__ float a3[400];
    __shared__ float f5[120];
    __shared__ float f6[84];

    const int b = blockIdx.x;
    const int tid = threadIdx.x;

    for (int i = tid; i < 1176; i += 256) {
        int row = i / 14, c = i % 14;
        a2[row * 18 + c] = out2[(size_t)b * 1176 + i];
    }
    __syncthreads();

    for (int t = tid; t < 400; t += 256) {
        const int oc = t / 25;
        const int rr = t % 25;
        const int py = rr / 5, px = rr % 5;
        const int x0 = px * 2, y0 = py * 2;
        float a00 = 0.f, a01 = 0.f, a10 = 0.f, a11 = 0.f;
#pragma unroll 1
        for (int ic = 0; ic < 6; ic++) {
            const float* wr = c3_w + (oc * 6 + ic) * 25;
            float w[25];
#pragma unroll
            for (int q = 0; q < 25; q++) w[q] = wr[q];
#pragma unroll
            for (int t6 = 0; t6 < 6; t6++) {
                float seg[6];
                const float2* sp = (const float2*)&a2[(ic * 14 + y0 + t6) * 18 + x0];
#pragma unroll
                for (int q = 0; q < 3; q++) {
                    float2 v = sp[q];
                    seg[2 * q] = v.x; seg[2 * q + 1] = v.y;
                }
                if (t6 < 5) {
#pragma unroll
                    for (int kx = 0; kx < 5; kx++) {
                        float wv = w[t6 * 5 + kx];
                        a00 += wv * seg[kx]; a01 += wv * seg[kx + 1];
                    }
                }
                if (t6 >= 1) {
#pragma unroll
                    for (int kx = 0; kx < 5; kx++) {
                        float wv = w[(t6 - 1) * 5 + kx];
                        a10 += wv * seg[kx]; a11 += wv * seg[kx + 1];
                    }
                }
            }
        }
        const float bb = c3_b[oc];
        a3[t] = 0.25f * (fast_tanh(a00 + bb) + fast_tanh(a01 + bb) +
                         fast_tanh(a10 + bb) + fast_tanh(a11 + bb));
    }
    __syncthreads();

    if (tid < 240) {
        const int o = tid >> 1;
        const int part = tid & 1;
        float acc = 0.0f;
        const float4* wp = (const float4*)(c5_w + (size_t)o * 400) + part * 50;
        const float4* ap = ((const float4*)a3) + part * 50;
#pragma unroll 5
        for (int q = 0; q < 50; q++) {
            float4 wv = wp[q], av = ap[q];
            acc += wv.x * av.x + wv.y * av.y + wv.z * av.z + wv.w * av.w;
        }
        acc += __shfl_xor(acc, 1);
        if (part == 0) f5[o] = fast_tanh(acc + c5_b[o]);
    }
    __syncthreads();

    if (tid < 84) {
        float acc = l1_b[tid];
        const float4* wp = (const float4*)(l1_w + tid * 120);
        const float4* fp = (const float4*)f5;
#pragma unroll
        for (int q = 0; q < 30; q++) {
            float4 wv = wp[q], fv = fp[q];
            acc += wv.x * fv.x + wv.y * fv.y + wv.z * fv.z + wv.w * fv.w;
        }
        f6[tid] = fast_tanh(acc);
    }
    __syncthreads();

    if (tid < 10) {
        float acc = l2_b[tid];
        const float* wp = l2_w + tid * 84;
#pragma unroll
        for (int q = 0; q < 84; q++) acc += wp[q] * f6[q];
        out[(size_t)b * 10 + tid] = acc;
    }
}

extern "C" void kernel_launch(void* const* d_in, const int* in_sizes, int n_in,
                              void* d_out, int out_size, void* d_ws, size_t ws_size,
                              hipStream_t stream) {
    const float* x       = (const float*)d_in[0];
    const float* filters = (const float*)d_in[1];
    const float* c1_w    = (const float*)d_in[2];
    const float* c1_b    = (const float*)d_in[3];
    const float* c3_w    = (const float*)d_in[4];
    const float* c3_b    = (const float*)d_in[5];
    const float* c5_w    = (const float*)d_in[6];
    const float* c5_b    = (const float*)d_in[7];
    const float* l1_w    = (const float*)d_in[8];
    const float* l1_b    = (const float*)d_in[9];
    const float* l2_w    = (const float*)d_in[10];
    const float* l2_b    = (const float*)d_in[11];
    float* out = (float*)d_out;

    const int B = in_sizes[0] / 1024;

    // ws: [w0mf: 256 u32 @0][w1mf: 4096 u32 @1024][out2 @17408]
    unsigned int* w0mf = (unsigned int*)d_ws;
    unsigned int* w1mf = (unsigned int*)((char*)d_ws + 1024);
    float* out2 = (float*)((char*)d_ws + 17408);

    pack_weights<<<17, 256, 0, stream>>>(c1_w, filters, w0mf, w1mf);
    lenet_front<<<B, 512, 0, stream>>>(x, w0mf, w1mf, c1_b, out2);
    lenet_back<<<B, 256, 0, stream>>>(out2, c3_w, c3_b, c5_w, c5_b,
                                      l1_w, l1_b, l2_w, l2_b, out);
}

// Round 17
// 229.083 us; speedup vs baseline: 1.3782x; 1.1206x over previous
//
#include <hip/hip_runtime.h>
#include <hip/hip_bf16.h>
#include <cstddef>

typedef _Float16 h2 __attribute__((ext_vector_type(2)));
typedef _Float16 half8 __attribute__((ext_vector_type(8)));
typedef float f32x4 __attribute__((ext_vector_type(4)));
typedef __fp16 fp16x2 __attribute__((ext_vector_type(2)));

// tanh via exp + hardware rcp (1-ulp): 1 - 2*rcp(e^{2x}+1).
// x>>0: e=inf, rcp=0 -> 1.  x<<0: e=0, rcp(1)=1 -> -1.
__device__ __forceinline__ float fast_tanh(float x) {
    float e = __expf(2.0f * x);
    return 1.0f - 2.0f * __builtin_amdgcn_rcpf(e + 1.0f);
}
__device__ __forceinline__ unsigned int pkrtz(float a, float b) {
    fp16x2 r = __builtin_amdgcn_cvt_pkrtz(a, b);
    union { fp16x2 h; unsigned int u; } v; v.h = r; return v.u;
}
__device__ __forceinline__ unsigned int pkh(float a, float b) {
    union { _Float16 h; unsigned short u; } x, y;
    x.h = (_Float16)a; y.h = (_Float16)b;
    return ((unsigned int)y.u << 16) | (unsigned int)x.u;
}
__device__ __forceinline__ float fdot2u(unsigned int a, unsigned int b, float c) {
    union U { unsigned int u; h2 h; };
    U ua; ua.u = a;
    U ub; ub.u = b;
    return __builtin_amdgcn_fdot2(ua.h, ub.h, c, false);
}

// K-pair slot tables (round-7 HW-verified): p = 4*h + d. Each read
// instruction's 4 h-group bank bases (6*ty+tx mod 32) form {a,a+16,b,b+16}
// -> 2 lanes/bank (free). p0..14 real (ty 0..4, tx 0/2/4), p15 zero slot.
#define TY64 0x11B44891A440ULL      // 3 bits per p
#define TX64 0xF120120120120120ULL  // 4 bits per p, value = tx/2
#define XST 38                      // s1p row stride in dwords; 38 mod 32 = 6
#define S1SZ 19488                  // max write/read 19479; 2 blocks/CU fits

__device__ __forceinline__ void slotf(int p, int& ty, int& tx) {
    ty = (int)((TY64 >> (3 * p)) & 7);
    tx = (int)((TX64 >> (4 * p)) & 15) * 2;
}

// ---------------------------------------------------------------------------
// pack: w0mf/w1mf (r7 verbatim) + c3pk (conv3 dual-parity dot2 pairs, r4 pattern)
__global__ void pack_weights(const float* __restrict__ c1_w,
                             const float* __restrict__ filters,
                             const float* __restrict__ c3_w,
                             unsigned int* __restrict__ w0mf,   // [4h][16oc][4d]
                             unsigned int* __restrict__ w1mf,   // [16ic][4h][16oc][4d]
                             unsigned int* __restrict__ c3pk) { // [16oc*6ic][32]
    int t = blockIdx.x * blockDim.x + threadIdx.x;
    if (t < 256) {
        int d = t & 3, oc = (t >> 2) & 15, hh = (t >> 6) & 3;
        int p = 4 * hh + d, ty, tx; slotf(p, ty, tx);
        float lo = 0.f, hi = 0.f;
        if (p != 15) {
            const float* w = filters + oc * 25 + ty * 5 + tx;
            lo = w[0]; hi = (tx < 4) ? w[1] : 0.f;
        }
        w0mf[t] = pkh(lo, hi);
    } else if (t < 256 + 4096) {
        int g = t - 256;
        int d = g & 3, oc = (g >> 2) & 15, hh = (g >> 6) & 3, ic = g >> 8;
        int p = 4 * hh + d, ty, tx; slotf(p, ty, tx);
        float lo = 0.f, hi = 0.f;
        if (p != 15 && oc < 6) {
            const float* w = c1_w + (oc * 16 + ic) * 25 + ty * 5 + tx;
            lo = w[0]; hi = (tx < 4) ? w[1] : 0.f;
        }
        w1mf[g] = pkh(lo, hi);
    } else if (t >= 4352 && t < 4352 + 480) {
        int g = t - 4352;
        int oc = g / 30, rem = g % 30, ic = rem / 5, ky = rem % 5;
        const float* w = c3_w + (oc * 6 + ic) * 25 + ky * 5;
        unsigned int* d = c3pk + (oc * 6 + ic) * 32 + ky * 6;
        d[0] = pkh(w[0], w[1]); d[1] = pkh(w[2], w[3]); d[2] = pkh(w[4], 0.f);
        d[3] = pkh(0.f, w[0]); d[4] = pkh(w[1], w[2]); d[5] = pkh(w[3], w[4]);
        if (ky == 0) {
            unsigned int* p2 = c3pk + (oc * 6 + ic) * 32;
            p2[30] = 0u; p2[31] = 0u;
        }
    }
}

// ---------------------------------------------------------------------------
// Front (r16 verbatim, rcp-tanh): aliased staging -> conv0 MFMA -> s1p
// (stride 38, ch*2 stagger) -> conv1 MFMA + bias + tanh + pool -> out2.
// LDS: 77952 B -> 2 blocks/CU, 16 waves/CU.
__global__ __launch_bounds__(512, 2) void lenet_front(
    const float* __restrict__ x,            // [B,1,32,32]
    const unsigned int* __restrict__ w0mf,
    const unsigned int* __restrict__ w1mf,
    const float* __restrict__ c1_b,         // [6]
    float* __restrict__ out2)               // [B,6,14,14]
{
    __shared__ unsigned int s1p[S1SZ];  // dwords 0..1367 double as input staging

    const int b = blockIdx.x;
    const int tid = threadIdx.x;
    const int lane = tid & 63;
    const int wid = tid >> 6;        // 0..7
    const int h = (lane >> 4) & 3;
    const int c = lane & 15;
    const float* xb = x + (size_t)b * 1024;

    for (int i = tid; i < S1SZ; i += 512) s1p[i] = 0u;

    int offd[4];
#pragma unroll
    for (int d = 0; d < 4; ++d) {
        int p = 4 * h + d, ty, tx; slotf(p, ty, tx);
        offd[d] = ty * XST + tx + c;
    }
    half8 af0 = *(const half8*)(w0mf + (h * 16 + c) * 4);
    __syncthreads();

    // ---- P0: input -> pair-dup f16 rows (alias region)
    {
        int r = tid >> 4, cc = tid & 15;
        float2 v = *(const float2*)(xb + r * 32 + cc * 2);
        float vnext = __shfl(v.x, lane + 1);
        if (cc == 15) vnext = 0.f;
        unsigned int d0 = pkrtz(v.x, v.y);
        unsigned int d1 = pkrtz(v.y, vnext);
        unsigned int* row = &s1p[(r + 2) * XST];
        *(uint2*)&row[2 * cc + 2] = make_uint2(d0, d1);
        if (cc == 0) row[1] = pkrtz(0.f, v.x);
    }
    __syncthreads();

    union H8 { unsigned int u[4]; half8 hv; };

    // ---- P1a: conv0 MFMA, inputs consumed into regs
    f32x4 AC0[4], AC1[4];
#pragma unroll
    for (int yi = 0; yi < 4; ++yi) {
        const int y = 4 * wid + yi;
        const int base = y * XST;
        H8 B0, B1;
#pragma unroll
        for (int d = 0; d < 4; ++d) {
            B0.u[d] = s1p[base + offd[d]];
            B1.u[d] = s1p[base + 16 + offd[d]];
        }
        f32x4 z = {0.f, 0.f, 0.f, 0.f};
        AC0[yi] = __builtin_amdgcn_mfma_f32_16x16x32_f16(af0, B0.hv, z, 0, 0, 0);
        AC1[yi] = __builtin_amdgcn_mfma_f32_16x16x32_f16(af0, B1.hv, z, 0, 0, 0);
    }
    __syncthreads();   // staging reads done -> safe to overwrite alias

    // ---- P1b: tanh + pair-dup writes, ch*2 stagger
#pragma unroll
    for (int yi = 0; yi < 4; ++yi) {
        const int y = 4 * wid + yi;
#pragma unroll
        for (int r = 0; r < 4; ++r) {
            int ch = 4 * h + r;
            float t0 = fast_tanh(AC0[yi][r]), t1 = fast_tanh(AC1[yi][r]);
            float t0n = __shfl(t0, lane + 1);
            float t1n = __shfl(t1, lane + 1);
            float tb  = __shfl(t1, lane & 48);
            float n0 = (c < 15) ? t0n : tb;
            float n1 = (c < 15) ? t1n : 0.f;
            int rb = (ch * 32 + y) * XST + ch * 2;
            s1p[rb + c]      = pkrtz(t0, n0);
            s1p[rb + 16 + c] = pkrtz(t1, n1);
        }
    }
    __syncthreads();

    // ---- P2: conv1 MFMA slot-table reads + setprio + epilogue
    half8 af[16];
#pragma unroll
    for (int ks = 0; ks < 16; ks++)
        af[ks] = *(const half8*)(w1mf + ((ks * 4 + h) * 16 + c) * 4);

    float bias_l[4];
#pragma unroll
    for (int r = 0; r < 4; r++) {
        int rr = 4 * h + r;
        bias_l[r] = c1_b[rr < 6 ? rr : 5];
    }

#pragma unroll 1
    for (int q = wid; q < 28; q += 8) {
        const int py = q >> 1;
        const int xh = q & 1;
        const int x0 = 12 * xh;
        const int yy = 2 * py;

        f32x4 acc0 = {0.f, 0.f, 0.f, 0.f};
        f32x4 acc1 = {0.f, 0.f, 0.f, 0.f};
        __builtin_amdgcn_s_setprio(1);
#pragma unroll
        for (int ks = 0; ks < 16; ks++) {
            const int kb = (ks * 32 + yy) * XST + ks * 2 + x0;
            H8 B0, B1;
#pragma unroll
            for (int d = 0; d < 4; ++d) {
                B0.u[d] = s1p[kb + offd[d]];
                B1.u[d] = s1p[kb + XST + offd[d]];
            }
            acc0 = __builtin_amdgcn_mfma_f32_16x16x32_f16(af[ks], B0.hv, acc0, 0, 0, 0);
            acc1 = __builtin_amdgcn_mfma_f32_16x16x32_f16(af[ks], B1.hv, acc1, 0, 0, 0);
        }
        __builtin_amdgcn_s_setprio(0);
#pragma unroll
        for (int r = 0; r < 4; r++) {
            int rr = 4 * h + r;
            float t = fast_tanh(acc0[r] + bias_l[r]) + fast_tanh(acc1[r] + bias_l[r]);
            t += __shfl_xor(t, 1);
            int pq = (c >> 1) + 6 * xh;
            bool ok = (rr < 6) && ((c & 1) == 0) && (xh ? (pq >= 7) : (pq <= 6));
            if (ok) out2[((size_t)b * 6 + rr) * 196 + py * 14 + pq] = 0.25f * t;
        }
    }
}

// ---------------------------------------------------------------------------
// Back: a2 f32 -> f16 pairs; conv3 via dual-parity dot2 (r4-verified pattern)
// -> c5 -> fc1 -> fc2 (r5 verbatim).
__global__ __launch_bounds__(256) void lenet_back(
    const float* __restrict__ out2,
    const unsigned int* __restrict__ c3pk, const float* __restrict__ c3_b,
    const float* __restrict__ c5_w, const float* __restrict__ c5_b,
    const float* __restrict__ l1_w, const float* __restrict__ l1_b,
    const float* __restrict__ l2_w, const float* __restrict__ l2_b,
    float* __restrict__ out)
{
    __shared__ unsigned int a2f[6 * 14 * 9];  // f16 pairs, 9-dword rows (7 + pad)
    __shared__ float a3[400];
    __shared__ float f5[120];
    __shared__ float f6[84];

    const int b = blockIdx.x;
    const int tid = threadIdx.x;

    // load out2 + pack to f16 pairs: row r (0..83), pair j (0..6)
    for (int i = tid; i < 588; i += 256) {
        int r = i / 7, j = i % 7;
        const float2 v = *(const float2*)(out2 + (size_t)b * 1176 + r * 14 + 2 * j);
        a2f[r * 9 + j] = pkh(v.x, v.y);
    }
    __syncthreads();

    // conv3 + bias + tanh + pool: 400 tasks, dual-parity dot2
    for (int t = tid; t < 400; t += 256) {
        const int oc = t / 25;
        const int rr = t % 25;
        const int py = rr / 5, px = rr % 5;
        const int y0 = py * 2;
        float a00 = 0.f, a01 = 0.f, a10 = 0.f, a11 = 0.f;
#pragma unroll 1
        for (int ic = 0; ic < 6; ic++) {
            unsigned int wu[32];
            const uint4* wb = (const uint4*)(c3pk + (oc * 6 + ic) * 32);
#pragma unroll
            for (int q = 0; q < 8; q++) {
                uint4 v = wb[q];
                wu[4 * q + 0] = v.x; wu[4 * q + 1] = v.y;
                wu[4 * q + 2] = v.z; wu[4 * q + 3] = v.w;
            }
#pragma unroll
            for (int t6 = 0; t6 < 6; t6++) {
                const unsigned int* sp = &a2f[(ic * 14 + y0 + t6) * 9 + px];
                unsigned int s0 = sp[0], s1 = sp[1], s2 = sp[2];
                if (t6 < 5) {  // output row y0, ky = t6
                    const int kb = t6 * 6;
                    a00 = fdot2u(wu[kb + 0], s0, a00);
                    a00 = fdot2u(wu[kb + 1], s1, a00);
                    a00 = fdot2u(wu[kb + 2], s2, a00);
                    a01 = fdot2u(wu[kb + 3], s0, a01);
                    a01 = fdot2u(wu[kb + 4], s1, a01);
                    a01 = fdot2u(wu[kb + 5], s2, a01);
                }
                if (t6 >= 1) {  // output row y0+1, ky = t6-1
                    const int kb = (t6 - 1) * 6;
                    a10 = fdot2u(wu[kb + 0], s0, a10);
                    a10 = fdot2u(wu[kb + 1], s1, a10);
                    a10 = fdot2u(wu[kb + 2], s2, a10);
                    a11 = fdot2u(wu[kb + 3], s0, a11);
                    a11 = fdot2u(wu[kb + 4], s1, a11);
                    a11 = fdot2u(wu[kb + 5], s2, a11);
                }
            }
        }
        const float bb = c3_b[oc];
        a3[t] = 0.25f * (fast_tanh(a00 + bb) + fast_tanh(a01 + bb) +
                         fast_tanh(a10 + bb) + fast_tanh(a11 + bb));
    }
    __syncthreads();

    if (tid < 240) {
        const int o = tid >> 1;
        const int part = tid & 1;
        float acc = 0.0f;
        const float4* wp = (const float4*)(c5_w + (size_t)o * 400) + part * 50;
        const float4* ap = ((const float4*)a3) + part * 50;
#pragma unroll 5
        for (int q = 0; q < 50; q++) {
            float4 wv = wp[q], av = ap[q];
            acc += wv.x * av.x + wv.y * av.y + wv.z * av.z + wv.w * av.w;
        }
        acc += __shfl_xor(acc, 1);
        if (part == 0) f5[o] = fast_tanh(acc + c5_b[o]);
    }
    __syncthreads();

    if (tid < 84) {
        float acc = l1_b[tid];
        const float4* wp = (const float4*)(l1_w + tid * 120);
        const float4* fp = (const float4*)f5;
#pragma unroll
        for (int q = 0; q < 30; q++) {
            float4 wv = wp[q], fv = fp[q];
            acc += wv.x * fv.x + wv.y * fv.y + wv.z * fv.z + wv.w * fv.w;
        }
        f6[tid] = fast_tanh(acc);
    }
    __syncthreads();

    if (tid < 10) {
        float acc = l2_b[tid];
        const float* wp = l2_w + tid * 84;
#pragma unroll
        for (int q = 0; q < 84; q++) acc += wp[q] * f6[q];
        out[(size_t)b * 10 + tid] = acc;
    }
}

extern "C" void kernel_launch(void* const* d_in, const int* in_sizes, int n_in,
                              void* d_out, int out_size, void* d_ws, size_t ws_size,
                              hipStream_t stream) {
    const float* x       = (const float*)d_in[0];
    const float* filters = (const float*)d_in[1];
    const float* c1_w    = (const float*)d_in[2];
    const float* c1_b    = (const float*)d_in[3];
    const float* c3_w    = (const float*)d_in[4];
    const float* c3_b    = (const float*)d_in[5];
    const float* c5_w    = (const float*)d_in[6];
    const float* c5_b    = (const float*)d_in[7];
    const float* l1_w    = (const float*)d_in[8];
    const float* l1_b    = (const float*)d_in[9];
    const float* l2_w    = (const float*)d_in[10];
    const float* l2_b    = (const float*)d_in[11];
    float* out = (float*)d_out;

    const int B = in_sizes[0] / 1024;

    // ws: [w0mf: 256 u32 @0][w1mf: 4096 u32 @1024][c3pk: 3072 u32 @17408][out2 @29696]
    unsigned int* w0mf = (unsigned int*)d_ws;
    unsigned int* w1mf = (unsigned int*)((char*)d_ws + 1024);
    unsigned int* c3pk = (unsigned int*)((char*)d_ws + 17408);
    float* out2 = (float*)((char*)d_ws + 29696);

    pack_weights<<<19, 256, 0, stream>>>(c1_w, filters, c3_w, w0mf, w1mf, c3pk);
    lenet_front<<<B, 512, 0, stream>>>(x, w0mf, w1mf, c1_b, out2);
    lenet_back<<<B, 256, 0, stream>>>(out2, c3pk, c3_b, c5_w, c5_b,
                                      l1_w, l1_b, l2_w, l2_b, out);
}

// Round 18
// 182.009 us; speedup vs baseline: 1.7347x; 1.2586x over previous
//
#include <hip/hip_runtime.h>
#include <hip/hip_bf16.h>
#include <cstddef>

typedef _Float16 h2 __attribute__((ext_vector_type(2)));
typedef _Float16 half8 __attribute__((ext_vector_type(8)));
typedef float f32x4 __attribute__((ext_vector_type(4)));
typedef __fp16 fp16x2 __attribute__((ext_vector_type(2)));

// tanh via exp + hardware rcp (1-ulp): 1 - 2*rcp(e^{2x}+1).
__device__ __forceinline__ float fast_tanh(float x) {
    float e = __expf(2.0f * x);
    return 1.0f - 2.0f * __builtin_amdgcn_rcpf(e + 1.0f);
}
__device__ __forceinline__ unsigned int pkrtz(float a, float b) {
    fp16x2 r = __builtin_amdgcn_cvt_pkrtz(a, b);
    union { fp16x2 h; unsigned int u; } v; v.h = r; return v.u;
}
__device__ __forceinline__ unsigned int pkh(float a, float b) {
    union { _Float16 h; unsigned short u; } x, y;
    x.h = (_Float16)a; y.h = (_Float16)b;
    return ((unsigned int)y.u << 16) | (unsigned int)x.u;
}
__device__ __forceinline__ float fdot2u(unsigned int a, unsigned int b, float c) {
    union U { unsigned int u; h2 h; };
    U ua; ua.u = a;
    U ub; ub.u = b;
    return __builtin_amdgcn_fdot2(ua.h, ub.h, c, false);
}

// K-pair slot tables (round-7 HW-verified): p = 4*h + d.
#define TY64 0x11B44891A440ULL      // 3 bits per p
#define TX64 0xF120120120120120ULL  // 4 bits per p, value = tx/2
#define XST 38                      // s1p row stride in dwords; 38 mod 32 = 6
#define S1SZ 19488                  // max write/read 19479; 2 blocks/CU fits
#define IMGS 4                      // images per back block (weight reuse)

__device__ __forceinline__ void slotf(int p, int& ty, int& tx) {
    ty = (int)((TY64 >> (3 * p)) & 7);
    tx = (int)((TX64 >> (4 * p)) & 15) * 2;
}

// ---------------------------------------------------------------------------
// pack (r17 verbatim): w0mf/w1mf + c3pk
__global__ void pack_weights(const float* __restrict__ c1_w,
                             const float* __restrict__ filters,
                             const float* __restrict__ c3_w,
                             unsigned int* __restrict__ w0mf,
                             unsigned int* __restrict__ w1mf,
                             unsigned int* __restrict__ c3pk) {
    int t = blockIdx.x * blockDim.x + threadIdx.x;
    if (t < 256) {
        int d = t & 3, oc = (t >> 2) & 15, hh = (t >> 6) & 3;
        int p = 4 * hh + d, ty, tx; slotf(p, ty, tx);
        float lo = 0.f, hi = 0.f;
        if (p != 15) {
            const float* w = filters + oc * 25 + ty * 5 + tx;
            lo = w[0]; hi = (tx < 4) ? w[1] : 0.f;
        }
        w0mf[t] = pkh(lo, hi);
    } else if (t < 256 + 4096) {
        int g = t - 256;
        int d = g & 3, oc = (g >> 2) & 15, hh = (g >> 6) & 3, ic = g >> 8;
        int p = 4 * hh + d, ty, tx; slotf(p, ty, tx);
        float lo = 0.f, hi = 0.f;
        if (p != 15 && oc < 6) {
            const float* w = c1_w + (oc * 16 + ic) * 25 + ty * 5 + tx;
            lo = w[0]; hi = (tx < 4) ? w[1] : 0.f;
        }
        w1mf[g] = pkh(lo, hi);
    } else if (t >= 4352 && t < 4352 + 480) {
        int g = t - 4352;
        int oc = g / 30, rem = g % 30, ic = rem / 5, ky = rem % 5;
        const float* w = c3_w + (oc * 6 + ic) * 25 + ky * 5;
        unsigned int* d = c3pk + (oc * 6 + ic) * 32 + ky * 6;
        d[0] = pkh(w[0], w[1]); d[1] = pkh(w[2], w[3]); d[2] = pkh(w[4], 0.f);
        d[3] = pkh(0.f, w[0]); d[4] = pkh(w[1], w[2]); d[5] = pkh(w[3], w[4]);
        if (ky == 0) {
            unsigned int* p2 = c3pk + (oc * 6 + ic) * 32;
            p2[30] = 0u; p2[31] = 0u;
        }
    }
}

// ---------------------------------------------------------------------------
// Front (r17 verbatim): aliased staging -> conv0 MFMA -> s1p -> conv1 MFMA
// + bias + tanh + pool -> out2.  LDS 77952 B -> 2 blocks/CU, 16 waves/CU.
__global__ __launch_bounds__(512, 2) void lenet_front(
    const float* __restrict__ x,
    const unsigned int* __restrict__ w0mf,
    const unsigned int* __restrict__ w1mf,
    const float* __restrict__ c1_b,
    float* __restrict__ out2)
{
    __shared__ unsigned int s1p[S1SZ];

    const int b = blockIdx.x;
    const int tid = threadIdx.x;
    const int lane = tid & 63;
    const int wid = tid >> 6;
    const int h = (lane >> 4) & 3;
    const int c = lane & 15;
    const float* xb = x + (size_t)b * 1024;

    for (int i = tid; i < S1SZ; i += 512) s1p[i] = 0u;

    int offd[4];
#pragma unroll
    for (int d = 0; d < 4; ++d) {
        int p = 4 * h + d, ty, tx; slotf(p, ty, tx);
        offd[d] = ty * XST + tx + c;
    }
    half8 af0 = *(const half8*)(w0mf + (h * 16 + c) * 4);
    __syncthreads();

    // P0: input -> pair-dup f16 rows (alias region)
    {
        int r = tid >> 4, cc = tid & 15;
        float2 v = *(const float2*)(xb + r * 32 + cc * 2);
        float vnext = __shfl(v.x, lane + 1);
        if (cc == 15) vnext = 0.f;
        unsigned int d0 = pkrtz(v.x, v.y);
        unsigned int d1 = pkrtz(v.y, vnext);
        unsigned int* row = &s1p[(r + 2) * XST];
        *(uint2*)&row[2 * cc + 2] = make_uint2(d0, d1);
        if (cc == 0) row[1] = pkrtz(0.f, v.x);
    }
    __syncthreads();

    union H8 { unsigned int u[4]; half8 hv; };

    // P1a: conv0 MFMA into regs
    f32x4 AC0[4], AC1[4];
#pragma unroll
    for (int yi = 0; yi < 4; ++yi) {
        const int y = 4 * wid + yi;
        const int base = y * XST;
        H8 B0, B1;
#pragma unroll
        for (int d = 0; d < 4; ++d) {
            B0.u[d] = s1p[base + offd[d]];
            B1.u[d] = s1p[base + 16 + offd[d]];
        }
        f32x4 z = {0.f, 0.f, 0.f, 0.f};
        AC0[yi] = __builtin_amdgcn_mfma_f32_16x16x32_f16(af0, B0.hv, z, 0, 0, 0);
        AC1[yi] = __builtin_amdgcn_mfma_f32_16x16x32_f16(af0, B1.hv, z, 0, 0, 0);
    }
    __syncthreads();

    // P1b: tanh + pair-dup writes, ch*2 stagger
#pragma unroll
    for (int yi = 0; yi < 4; ++yi) {
        const int y = 4 * wid + yi;
#pragma unroll
        for (int r = 0; r < 4; ++r) {
            int ch = 4 * h + r;
            float t0 = fast_tanh(AC0[yi][r]), t1 = fast_tanh(AC1[yi][r]);
            float t0n = __shfl(t0, lane + 1);
            float t1n = __shfl(t1, lane + 1);
            float tb  = __shfl(t1, lane & 48);
            float n0 = (c < 15) ? t0n : tb;
            float n1 = (c < 15) ? t1n : 0.f;
            int rb = (ch * 32 + y) * XST + ch * 2;
            s1p[rb + c]      = pkrtz(t0, n0);
            s1p[rb + 16 + c] = pkrtz(t1, n1);
        }
    }
    __syncthreads();

    // P2: conv1 MFMA + setprio + epilogue
    half8 af[16];
#pragma unroll
    for (int ks = 0; ks < 16; ks++)
        af[ks] = *(const half8*)(w1mf + ((ks * 4 + h) * 16 + c) * 4);

    float bias_l[4];
#pragma unroll
    for (int r = 0; r < 4; r++) {
        int rr = 4 * h + r;
        bias_l[r] = c1_b[rr < 6 ? rr : 5];
    }

#pragma unroll 1
    for (int q = wid; q < 28; q += 8) {
        const int py = q >> 1;
        const int xh = q & 1;
        const int x0 = 12 * xh;
        const int yy = 2 * py;

        f32x4 acc0 = {0.f, 0.f, 0.f, 0.f};
        f32x4 acc1 = {0.f, 0.f, 0.f, 0.f};
        __builtin_amdgcn_s_setprio(1);
#pragma unroll
        for (int ks = 0; ks < 16; ks++) {
            const int kb = (ks * 32 + yy) * XST + ks * 2 + x0;
            H8 B0, B1;
#pragma unroll
            for (int d = 0; d < 4; ++d) {
                B0.u[d] = s1p[kb + offd[d]];
                B1.u[d] = s1p[kb + XST + offd[d]];
            }
            acc0 = __builtin_amdgcn_mfma_f32_16x16x32_f16(af[ks], B0.hv, acc0, 0, 0, 0);
            acc1 = __builtin_amdgcn_mfma_f32_16x16x32_f16(af[ks], B1.hv, acc1, 0, 0, 0);
        }
        __builtin_amdgcn_s_setprio(0);
#pragma unroll
        for (int r = 0; r < 4; r++) {
            int rr = 4 * h + r;
            float t = fast_tanh(acc0[r] + bias_l[r]) + fast_tanh(acc1[r] + bias_l[r]);
            t += __shfl_xor(t, 1);
            int pq = (c >> 1) + 6 * xh;
            bool ok = (rr < 6) && ((c & 1) == 0) && (xh ? (pq >= 7) : (pq <= 6));
            if (ok) out2[((size_t)b * 6 + rr) * 196 + py * 14 + pq] = 0.25f * t;
        }
    }
}

// ---------------------------------------------------------------------------
// Back (r17 math, IMGS=4 per block, weights loaded once and reused):
// a2 f32->f16; conv3 dual-parity dot2 -> c5 -> fc1 -> fc2.
__global__ __launch_bounds__(256) void lenet_back(
    const float* __restrict__ out2,
    const unsigned int* __restrict__ c3pk, const float* __restrict__ c3_b,
    const float* __restrict__ c5_w, const float* __restrict__ c5_b,
    const float* __restrict__ l1_w, const float* __restrict__ l1_b,
    const float* __restrict__ l2_w, const float* __restrict__ l2_b,
    float* __restrict__ out, int B)
{
    __shared__ unsigned int a2f[IMGS][84 * 9];
    __shared__ __align__(16) float a3[IMGS][400];
    __shared__ float f5[IMGS][120];
    __shared__ float f6[IMGS][84];

    const int b0 = blockIdx.x * IMGS;
    const int tid = threadIdx.x;

    // load + pack f32 -> f16 pairs, 4 images
    for (int i = tid; i < 588 * IMGS; i += 256) {
        int img = i / 588, rem = i % 588;
        int r = rem / 7, j = rem % 7;
        unsigned int pv = 0u;
        if (b0 + img < B) {
            const float2 v = *(const float2*)(out2 + (size_t)(b0 + img) * 1176 + r * 14 + 2 * j);
            pv = pkh(v.x, v.y);
        }
        a2f[img][r * 9 + j] = pv;
    }
    __syncthreads();

    // conv3 + bias + tanh + pool: 400 tasks x 4 images, weights reused
    for (int t = tid; t < 400; t += 256) {
        const int oc = t / 25;
        const int rr = t % 25;
        const int py = rr / 5, px = rr % 5;
        const int y0 = py * 2;
        float a00[IMGS], a01[IMGS], a10[IMGS], a11[IMGS];
#pragma unroll
        for (int g = 0; g < IMGS; g++) { a00[g] = 0.f; a01[g] = 0.f; a10[g] = 0.f; a11[g] = 0.f; }
#pragma unroll 1
        for (int ic = 0; ic < 6; ic++) {
            unsigned int wu[32];
            const uint4* wb = (const uint4*)(c3pk + (oc * 6 + ic) * 32);
#pragma unroll
            for (int q = 0; q < 8; q++) {
                uint4 v = wb[q];
                wu[4 * q + 0] = v.x; wu[4 * q + 1] = v.y;
                wu[4 * q + 2] = v.z; wu[4 * q + 3] = v.w;
            }
#pragma unroll
            for (int t6 = 0; t6 < 6; t6++) {
                const int rowoff = (ic * 14 + y0 + t6) * 9 + px;
#pragma unroll
                for (int g = 0; g < IMGS; g++) {
                    const unsigned int* sp = &a2f[g][rowoff];
                    unsigned int s0 = sp[0], s1 = sp[1], s2 = sp[2];
                    if (t6 < 5) {
                        const int kb = t6 * 6;
                        a00[g] = fdot2u(wu[kb + 0], s0, a00[g]);
                        a00[g] = fdot2u(wu[kb + 1], s1, a00[g]);
                        a00[g] = fdot2u(wu[kb + 2], s2, a00[g]);
                        a01[g] = fdot2u(wu[kb + 3], s0, a01[g]);
                        a01[g] = fdot2u(wu[kb + 4], s1, a01[g]);
                        a01[g] = fdot2u(wu[kb + 5], s2, a01[g]);
                    }
                    if (t6 >= 1) {
                        const int kb = (t6 - 1) * 6;
                        a10[g] = fdot2u(wu[kb + 0], s0, a10[g]);
                        a10[g] = fdot2u(wu[kb + 1], s1, a10[g]);
                        a10[g] = fdot2u(wu[kb + 2], s2, a10[g]);
                        a11[g] = fdot2u(wu[kb + 3], s0, a11[g]);
                        a11[g] = fdot2u(wu[kb + 4], s1, a11[g]);
                        a11[g] = fdot2u(wu[kb + 5], s2, a11[g]);
                    }
                }
            }
        }
        const float bb = c3_b[oc];
#pragma unroll
        for (int g = 0; g < IMGS; g++) {
            a3[g][t] = 0.25f * (fast_tanh(a00[g] + bb) + fast_tanh(a01[g] + bb) +
                                fast_tanh(a10[g] + bb) + fast_tanh(a11[g] + bb));
        }
    }
    __syncthreads();

    // c5: 120 outputs x 2 threads; weights reused across 4 images
    if (tid < 240) {
        const int o = tid >> 1;
        const int part = tid & 1;
        float acc[IMGS] = {0.f, 0.f, 0.f, 0.f};
        const float4* wp = (const float4*)(c5_w + (size_t)o * 400) + part * 50;
#pragma unroll 2
        for (int q = 0; q < 50; q++) {
            float4 wv = wp[q];
#pragma unroll
            for (int g = 0; g < IMGS; g++) {
                float4 av = ((const float4*)a3[g])[part * 50 + q];
                acc[g] += wv.x * av.x + wv.y * av.y + wv.z * av.z + wv.w * av.w;
            }
        }
#pragma unroll
        for (int g = 0; g < IMGS; g++) {
            acc[g] += __shfl_xor(acc[g], 1);
            if (part == 0) f5[g][o] = fast_tanh(acc[g] + c5_b[o]);
        }
    }
    __syncthreads();

    // fc1: 84 outputs; weights reused
    if (tid < 84) {
        float acc[IMGS];
        const float bb = l1_b[tid];
#pragma unroll
        for (int g = 0; g < IMGS; g++) acc[g] = bb;
        const float4* wp = (const float4*)(l1_w + tid * 120);
#pragma unroll 5
        for (int q = 0; q < 30; q++) {
            float4 wv = wp[q];
#pragma unroll
            for (int g = 0; g < IMGS; g++) {
                float4 fv = ((const float4*)f5[g])[q];
                acc[g] += wv.x * fv.x + wv.y * fv.y + wv.z * fv.z + wv.w * fv.w;
            }
        }
#pragma unroll
        for (int g = 0; g < IMGS; g++) f6[tid >= 0 ? g : g][tid] = fast_tanh(acc[g]);
    }
    __syncthreads();

    // fc2: 10 outputs; weights reused
    if (tid < 10) {
        float acc[IMGS];
        const float bb = l2_b[tid];
#pragma unroll
        for (int g = 0; g < IMGS; g++) acc[g] = bb;
        const float* wp = l2_w + tid * 84;
#pragma unroll 4
        for (int q = 0; q < 84; q++) {
            float w = wp[q];
#pragma unroll
            for (int g = 0; g < IMGS; g++) acc[g] += w * f6[g][q];
        }
#pragma unroll
        for (int g = 0; g < IMGS; g++)
            if (b0 + g < B) out[(size_t)(b0 + g) * 10 + tid] = acc[g];
    }
}

extern "C" void kernel_launch(void* const* d_in, const int* in_sizes, int n_in,
                              void* d_out, int out_size, void* d_ws, size_t ws_size,
                              hipStream_t stream) {
    const float* x       = (const float*)d_in[0];
    const float* filters = (const float*)d_in[1];
    const float* c1_w    = (const float*)d_in[2];
    const float* c1_b    = (const float*)d_in[3];
    const float* c3_w    = (const float*)d_in[4];
    const float* c3_b    = (const float*)d_in[5];
    const float* c5_w    = (const float*)d_in[6];
    const float* c5_b    = (const float*)d_in[7];
    const float* l1_w    = (const float*)d_in[8];
    const float* l1_b    = (const float*)d_in[9];
    const float* l2_w    = (const float*)d_in[10];
    const float* l2_b    = (const float*)d_in[11];
    float* out = (float*)d_out;

    const int B = in_sizes[0] / 1024;

    // ws: [w0mf @0][w1mf @1024][c3pk @17408][out2 @29696]
    unsigned int* w0mf = (unsigned int*)d_ws;
    unsigned int* w1mf = (unsigned int*)((char*)d_ws + 1024);
    unsigned int* c3pk = (unsigned int*)((char*)d_ws + 17408);
    float* out2 = (float*)((char*)d_ws + 29696);

    pack_weights<<<19, 256, 0, stream>>>(c1_w, filters, c3_w, w0mf, w1mf, c3pk);
    lenet_front<<<B, 512, 0, stream>>>(x, w0mf, w1mf, c1_b, out2);
    lenet_back<<<(B + IMGS - 1) / IMGS, 256, 0, stream>>>(
        out2, c3pk, c3_b, c5_w, c5_b, l1_w, l1_b, l2_w, l2_b, out, B);
}

// Round 19
// 143.855 us; speedup vs baseline: 2.1947x; 1.2652x over previous
//
#include <hip/hip_runtime.h>
#include <hip/hip_bf16.h>
#include <cstddef>

typedef _Float16 h2 __attribute__((ext_vector_type(2)));
typedef _Float16 half8 __attribute__((ext_vector_type(8)));
typedef float f32x4 __attribute__((ext_vector_type(4)));
typedef __fp16 fp16x2 __attribute__((ext_vector_type(2)));

// tanh via exp + hardware rcp (1-ulp): 1 - 2*rcp(e^{2x}+1).
__device__ __forceinline__ float fast_tanh(float x) {
    float e = __expf(2.0f * x);
    return 1.0f - 2.0f * __builtin_amdgcn_rcpf(e + 1.0f);
}
__device__ __forceinline__ unsigned int pkrtz(float a, float b) {
    fp16x2 r = __builtin_amdgcn_cvt_pkrtz(a, b);
    union { fp16x2 h; unsigned int u; } v; v.h = r; return v.u;
}
__device__ __forceinline__ unsigned int pkh(float a, float b) {
    union { _Float16 h; unsigned short u; } x, y;
    x.h = (_Float16)a; y.h = (_Float16)b;
    return ((unsigned int)y.u << 16) | (unsigned int)x.u;
}
__device__ __forceinline__ unsigned short f2h(float a) {
    union { _Float16 h; unsigned short u; } x;
    x.h = (_Float16)a; return x.u;
}
__device__ __forceinline__ float fdot2u(unsigned int a, unsigned int b, float c) {
    union U { unsigned int u; h2 h; };
    U ua; ua.u = a;
    U ub; ub.u = b;
    return __builtin_amdgcn_fdot2(ua.h, ub.h, c, false);
}

// conv0 staging slot tables (round-7 HW-verified): p = 4*h + d.
#define TY64 0x11B44891A440ULL      // 3 bits per p
#define TX64 0xF120120120120120ULL  // 4 bits per p, value = tx/2
#define XST 38                      // staging row stride in dwords
#define S1SZ 8448                   // s1: 32x32 pix x 8 dw + 256 dw row-32 pad
#define IMGS 4

__device__ __forceinline__ void slotf(int p, int& ty, int& tx) {
    ty = (int)((TY64 >> (3 * p)) & 7);
    tx = (int)((TX64 >> (4 * p)) & 15) * 2;
}

// ---------------------------------------------------------------------------
// pack: w0mf (conv0 A, r7) + c3pk (conv3 dot2, r17) + w1a (conv1 tap-pair A).
// w1a[(s*64+lane)*4+d]: lane(h,c): A[row=c][k=8h+2d(+1)], k=(tp=h>>1, ic=k&15),
// tap t = 2s+tp; value = c1_w[c][ic][t] (0 if c>=6 or t>=25).
__global__ void pack_weights(const float* __restrict__ c1_w,
                             const float* __restrict__ filters,
                             const float* __restrict__ c3_w,
                             unsigned int* __restrict__ w0mf,
                             unsigned int* __restrict__ c3pk,
                             unsigned int* __restrict__ w1a) {
    int t = blockIdx.x * blockDim.x + threadIdx.x;
    if (t < 256) {
        int d = t & 3, oc = (t >> 2) & 15, hh = (t >> 6) & 3;
        int p = 4 * hh + d, ty, tx; slotf(p, ty, tx);
        float lo = 0.f, hi = 0.f;
        if (p != 15) {
            const float* w = filters + oc * 25 + ty * 5 + tx;
            lo = w[0]; hi = (tx < 4) ? w[1] : 0.f;
        }
        w0mf[t] = pkh(lo, hi);
    } else if (t >= 4352 && t < 4352 + 480) {
        int g = t - 4352;
        int oc = g / 30, rem = g % 30, ic = rem / 5, ky = rem % 5;
        const float* w = c3_w + (oc * 6 + ic) * 25 + ky * 5;
        unsigned int* d = c3pk + (oc * 6 + ic) * 32 + ky * 6;
        d[0] = pkh(w[0], w[1]); d[1] = pkh(w[2], w[3]); d[2] = pkh(w[4], 0.f);
        d[3] = pkh(0.f, w[0]); d[4] = pkh(w[1], w[2]); d[5] = pkh(w[3], w[4]);
        if (ky == 0) {
            unsigned int* p2 = c3pk + (oc * 6 + ic) * 32;
            p2[30] = 0u; p2[31] = 0u;
        }
    } else if (t >= 4864 && t < 4864 + 3328) {
        int g = t - 4864;                 // = s*256 + lane*4 + d
        int s = g >> 8;
        int rem = g & 255;
        int lane = rem >> 2, d = rem & 3;
        int h = lane >> 4, c = lane & 15;
        int tt = 2 * s + (h >> 1);
        int icA = 8 * (h & 1) + 2 * d;
        float lo = 0.f, hi = 0.f;
        if (c < 6 && tt < 25) {
            lo = c1_w[(c * 16 + icA) * 25 + tt];
            hi = c1_w[(c * 16 + icA + 1) * 25 + tt];
        }
        w1a[g] = pkh(lo, hi);
    }
}

// ---------------------------------------------------------------------------
// Front: staging (r17 P0, aliased in s1[0..1368)) -> conv0 MFMA (r17 P1a) ->
// b16-scatter epilogue into s1 [pix][ic] (swizzle dw^=(x&12)) -> conv1 MFMA
// with tap-pair K-packing: per step one ds_read_b128 + offset-1024 twin.
// LDS 33792 B -> 2 blocks/CU.
__global__ __launch_bounds__(512, 2) void lenet_front(
    const float* __restrict__ x,
    const unsigned int* __restrict__ w0mf,
    const unsigned int* __restrict__ w1a,
    const float* __restrict__ c1_b,
    float* __restrict__ out2)
{
    __shared__ __align__(16) unsigned int s1[S1SZ];

    const int b = blockIdx.x;
    const int tid = threadIdx.x;
    const int lane = tid & 63;
    const int wid = tid >> 6;
    const int h = (lane >> 4) & 3;
    const int c = lane & 15;
    const float* xb = x + (size_t)b * 1024;

    // zero staging region + row-32 pad (rest is fully overwritten by P1b)
    for (int i = tid; i < 1368; i += 512) s1[i] = 0u;
    if (tid < 256) s1[8192 + tid] = 0u;

    // conv0 staging slot offsets (r7)
    int offd[4];
#pragma unroll
    for (int d = 0; d < 4; ++d) {
        int p = 4 * h + d, ty, tx; slotf(p, ty, tx);
        offd[d] = ty * XST + tx + c;
    }
    half8 af0 = *(const half8*)(w0mf + (h * 16 + c) * 4);

    // conv1 A-frags resident (13 x 4 VGPR)
    half8 afc[13];
#pragma unroll
    for (int s = 0; s < 13; s++)
        afc[s] = *(const half8*)(w1a + (s * 64 + lane) * 4);
    __syncthreads();

    // ---- P0 (r17 verbatim): input -> pair-dup f16 staging rows
    {
        int r = tid >> 4, cc = tid & 15;
        float2 v = *(const float2*)(xb + r * 32 + cc * 2);
        float vnext = __shfl(v.x, lane + 1);
        if (cc == 15) vnext = 0.f;
        unsigned int d0 = pkrtz(v.x, v.y);
        unsigned int d1 = pkrtz(v.y, vnext);
        unsigned int* row = &s1[(r + 2) * XST];
        *(uint2*)&row[2 * cc + 2] = make_uint2(d0, d1);
        if (cc == 0) row[1] = pkrtz(0.f, v.x);
    }
    __syncthreads();

    union H8 { unsigned int u[4]; half8 hv; };
    union U4H { uint4 u; half8 hv; };

    // ---- P1a (r17 verbatim): conv0 MFMA into regs
    f32x4 AC0[4], AC1[4];
#pragma unroll
    for (int yi = 0; yi < 4; ++yi) {
        const int y = 4 * wid + yi;
        const int base = y * XST;
        H8 B0, B1;
#pragma unroll
        for (int d = 0; d < 4; ++d) {
            B0.u[d] = s1[base + offd[d]];
            B1.u[d] = s1[base + 16 + offd[d]];
        }
        f32x4 z = {0.f, 0.f, 0.f, 0.f};
        AC0[yi] = __builtin_amdgcn_mfma_f32_16x16x32_f16(af0, B0.hv, z, 0, 0, 0);
        AC1[yi] = __builtin_amdgcn_mfma_f32_16x16x32_f16(af0, B1.hv, z, 0, 0, 0);
    }
    __syncthreads();   // staging consumed -> safe to overwrite

    // ---- P1b: tanh + b16 scatter into [pix][ic] layout, swizzle dw^=(x&12).
    // value(ch, pix=y*32+x) -> ushort idx = 2*((pix*8 + (ch>>1)) ^ (x&12)) + (ch&1)
    {
        unsigned short* us = (unsigned short*)s1;
#pragma unroll
        for (int yi = 0; yi < 4; ++yi) {
            const int y = 4 * wid + yi;
            const int ybase = y * 256;
#pragma unroll
            for (int r = 0; r < 4; ++r) {
                int ch = 4 * h + r;
                int qq = ch >> 1, lohi = ch & 1;
                unsigned short h0 = f2h(fast_tanh(AC0[yi][r]));
                unsigned short h1 = f2h(fast_tanh(AC1[yi][r]));
                int dw0 = (ybase + c * 8 + qq) ^ (c & 12);
                int dw1 = (ybase + (16 + c) * 8 + qq) ^ (c & 12);  // (16+c)&12 == c&12
                us[dw0 * 2 + lohi] = h0;
                us[dw1 * 2 + lohi] = h1;
            }
        }
    }
    __syncthreads();

    // ---- P2: conv1 MFMA, tap-pair K (13 steps), one b128 + twin per step
    const bool hi2 = (h >= 2);
    const int ih4 = 4 * (h & 1);
    const int xc_ = c;  // + x0 per tile

    float bias_l[4];
#pragma unroll
    for (int r = 0; r < 4; r++) {
        int rr = 4 * h + r;
        bias_l[r] = c1_b[rr < 6 ? rr : 5];
    }

#pragma unroll 1
    for (int q = wid; q < 28; q += 8) {
        const int py = q >> 1;
        const int xh = q & 1;
        const int x0 = 12 * xh;
        const int yy = 2 * py;
        const int xc = x0 + xc_;
        const int bk = yy * 256 + xc * 8 + ih4;

        f32x4 acc0 = {0.f, 0.f, 0.f, 0.f};
        f32x4 acc1 = {0.f, 0.f, 0.f, 0.f};
        __builtin_amdgcn_s_setprio(1);
#pragma unroll
        for (int s = 0; s < 13; s++) {
            const int t0 = 2 * s, t1 = 2 * s + 1;
            const int K0 = (t0 / 5) * 256 + (t0 % 5) * 8;
            const int K1 = (t1 / 5) * 256 + (t1 % 5) * 8;
            const int X0 = t0 % 5, X1 = t1 % 5;
            int Ks = hi2 ? K1 : K0;
            int txs = hi2 ? X1 : X0;
            int x2 = xc + txs;
            int dw = (bk + Ks) ^ (x2 & 12);
            U4H B0, B1;
            B0.u = *(const uint4*)&s1[dw];
            B1.u = *(const uint4*)&s1[dw + 256];   // conv row +1
            acc0 = __builtin_amdgcn_mfma_f32_16x16x32_f16(afc[s], B0.hv, acc0, 0, 0, 0);
            acc1 = __builtin_amdgcn_mfma_f32_16x16x32_f16(afc[s], B1.hv, acc1, 0, 0, 0);
        }
        __builtin_amdgcn_s_setprio(0);
#pragma unroll
        for (int r = 0; r < 4; r++) {
            int rr = 4 * h + r;
            float t = fast_tanh(acc0[r] + bias_l[r]) + fast_tanh(acc1[r] + bias_l[r]);
            t += __shfl_xor(t, 1);
            int pq = (c >> 1) + 6 * xh;
            bool ok = (rr < 6) && ((c & 1) == 0) && (xh ? (pq >= 7) : (pq <= 6));
            if (ok) out2[((size_t)b * 6 + rr) * 196 + py * 14 + pq] = 0.25f * t;
        }
    }
}

// ---------------------------------------------------------------------------
// Back (r18 verbatim, IMGS=4): a2 f32->f16; conv3 dot2 -> c5 -> fc1 -> fc2.
__global__ __launch_bounds__(256) void lenet_back(
    const float* __restrict__ out2,
    const unsigned int* __restrict__ c3pk, const float* __restrict__ c3_b,
    const float* __restrict__ c5_w, const float* __restrict__ c5_b,
    const float* __restrict__ l1_w, const float* __restrict__ l1_b,
    const float* __restrict__ l2_w, const float* __restrict__ l2_b,
    float* __restrict__ out, int B)
{
    __shared__ unsigned int a2f[IMGS][84 * 9];
    __shared__ __align__(16) float a3[IMGS][400];
    __shared__ float f5[IMGS][120];
    __shared__ float f6[IMGS][84];

    const int b0 = blockIdx.x * IMGS;
    const int tid = threadIdx.x;

    for (int i = tid; i < 588 * IMGS; i += 256) {
        int img = i / 588, rem = i % 588;
        int r = rem / 7, j = rem % 7;
        unsigned int pv = 0u;
        if (b0 + img < B) {
            const float2 v = *(const float2*)(out2 + (size_t)(b0 + img) * 1176 + r * 14 + 2 * j);
            pv = pkh(v.x, v.y);
        }
        a2f[img][r * 9 + j] = pv;
    }
    __syncthreads();

    for (int t = tid; t < 400; t += 256) {
        const int oc = t / 25;
        const int rr = t % 25;
        const int py = rr / 5, px = rr % 5;
        const int y0 = py * 2;
        float a00[IMGS], a01[IMGS], a10[IMGS], a11[IMGS];
#pragma unroll
        for (int g = 0; g < IMGS; g++) { a00[g] = 0.f; a01[g] = 0.f; a10[g] = 0.f; a11[g] = 0.f; }
#pragma unroll 1
        for (int ic = 0; ic < 6; ic++) {
            unsigned int wu[32];
            const uint4* wb = (const uint4*)(c3pk + (oc * 6 + ic) * 32);
#pragma unroll
            for (int qv = 0; qv < 8; qv++) {
                uint4 v = wb[qv];
                wu[4 * qv + 0] = v.x; wu[4 * qv + 1] = v.y;
                wu[4 * qv + 2] = v.z; wu[4 * qv + 3] = v.w;
            }
#pragma unroll
            for (int t6 = 0; t6 < 6; t6++) {
                const int rowoff = (ic * 14 + y0 + t6) * 9 + px;
#pragma unroll
                for (int g = 0; g < IMGS; g++) {
                    const unsigned int* sp = &a2f[g][rowoff];
                    unsigned int s0 = sp[0], s1v = sp[1], s2 = sp[2];
                    if (t6 < 5) {
                        const int kb = t6 * 6;
                        a00[g] = fdot2u(wu[kb + 0], s0, a00[g]);
                        a00[g] = fdot2u(wu[kb + 1], s1v, a00[g]);
                        a00[g] = fdot2u(wu[kb + 2], s2, a00[g]);
                        a01[g] = fdot2u(wu[kb + 3], s0, a01[g]);
                        a01[g] = fdot2u(wu[kb + 4], s1v, a01[g]);
                        a01[g] = fdot2u(wu[kb + 5], s2, a01[g]);
                    }
                    if (t6 >= 1) {
                        const int kb = (t6 - 1) * 6;
                        a10[g] = fdot2u(wu[kb + 0], s0, a10[g]);
                        a10[g] = fdot2u(wu[kb + 1], s1v, a10[g]);
                        a10[g] = fdot2u(wu[kb + 2], s2, a10[g]);
                        a11[g] = fdot2u(wu[kb + 3], s0, a11[g]);
                        a11[g] = fdot2u(wu[kb + 4], s1v, a11[g]);
                        a11[g] = fdot2u(wu[kb + 5], s2, a11[g]);
                    }
                }
            }
        }
        const float bb = c3_b[oc];
#pragma unroll
        for (int g = 0; g < IMGS; g++) {
            a3[g][t] = 0.25f * (fast_tanh(a00[g] + bb) + fast_tanh(a01[g] + bb) +
                                fast_tanh(a10[g] + bb) + fast_tanh(a11[g] + bb));
        }
    }
    __syncthreads();

    if (tid < 240) {
        const int o = tid >> 1;
        const int part = tid & 1;
        float acc[IMGS] = {0.f, 0.f, 0.f, 0.f};
        const float4* wp = (const float4*)(c5_w + (size_t)o * 400) + part * 50;
#pragma unroll 2
        for (int qv = 0; qv < 50; qv++) {
            float4 wv = wp[qv];
#pragma unroll
            for (int g = 0; g < IMGS; g++) {
                float4 av = ((const float4*)a3[g])[part * 50 + qv];
                acc[g] += wv.x * av.x + wv.y * av.y + wv.z * av.z + wv.w * av.w;
            }
        }
#pragma unroll
        for (int g = 0; g < IMGS; g++) {
            acc[g] += __shfl_xor(acc[g], 1);
            if (part == 0) f5[g][o] = fast_tanh(acc[g] + c5_b[o]);
        }
    }
    __syncthreads();

    if (tid < 84) {
        float acc[IMGS];
        const float bb = l1_b[tid];
#pragma unroll
        for (int g = 0; g < IMGS; g++) acc[g] = bb;
        const float4* wp = (const float4*)(l1_w + tid * 120);
#pragma unroll 5
        for (int qv = 0; qv < 30; qv++) {
            float4 wv = wp[qv];
#pragma unroll
            for (int g = 0; g < IMGS; g++) {
                float4 fv = ((const float4*)f5[g])[qv];
                acc[g] += wv.x * fv.x + wv.y * fv.y + wv.z * fv.z + wv.w * fv.w;
            }
        }
#pragma unroll
        for (int g = 0; g < IMGS; g++) f6[g][tid] = fast_tanh(acc[g]);
    }
    __syncthreads();

    if (tid < 10) {
        float acc[IMGS];
        const float bb = l2_b[tid];
#pragma unroll
        for (int g = 0; g < IMGS; g++) acc[g] = bb;
        const float* wp = l2_w + tid * 84;
#pragma unroll 4
        for (int qv = 0; qv < 84; qv++) {
            float w = wp[qv];
#pragma unroll
            for (int g = 0; g < IMGS; g++) acc[g] += w * f6[g][qv];
        }
#pragma unroll
        for (int g = 0; g < IMGS; g++)
            if (b0 + g < B) out[(size_t)(b0 + g) * 10 + tid] = acc[g];
    }
}

extern "C" void kernel_launch(void* const* d_in, const int* in_sizes, int n_in,
                              void* d_out, int out_size, void* d_ws, size_t ws_size,
                              hipStream_t stream) {
    const float* x       = (const float*)d_in[0];
    const float* filters = (const float*)d_in[1];
    const float* c1_w    = (const float*)d_in[2];
    const float* c1_b    = (const float*)d_in[3];
    const float* c3_w    = (const float*)d_in[4];
    const float* c3_b    = (const float*)d_in[5];
    const float* c5_w    = (const float*)d_in[6];
    const float* c5_b    = (const float*)d_in[7];
    const float* l1_w    = (const float*)d_in[8];
    const float* l1_b    = (const float*)d_in[9];
    const float* l2_w    = (const float*)d_in[10];
    const float* l2_b    = (const float*)d_in[11];
    float* out = (float*)d_out;

    const int B = in_sizes[0] / 1024;

    // ws: [w0mf: 256u32 @0][c3pk: 3072u32 @17408][w1a: 3328u32 @29696][out2 @43008]
    unsigned int* w0mf = (unsigned int*)d_ws;
    unsigned int* c3pk = (unsigned int*)((char*)d_ws + 17408);
    unsigned int* w1a  = (unsigned int*)((char*)d_ws + 29696);
    float* out2 = (float*)((char*)d_ws + 43008);

    pack_weights<<<32, 256, 0, stream>>>(c1_w, filters, c3_w, w0mf, c3pk, w1a);
    lenet_front<<<B, 512, 0, stream>>>(x, w0mf, w1a, c1_b, out2);
    lenet_back<<<(B + IMGS - 1) / IMGS, 256, 0, stream>>>(
        out2, c3pk, c3_b, c5_w, c5_b, l1_w, l1_b, l2_w, l2_b, out, B);
}

// Round 20
// 136.067 us; speedup vs baseline: 2.3204x; 1.0572x over previous
//
#include <hip/hip_runtime.h>
#include <hip/hip_bf16.h>
#include <cstddef>

typedef _Float16 h2 __attribute__((ext_vector_type(2)));
typedef _Float16 half8 __attribute__((ext_vector_type(8)));
typedef float f32x4 __attribute__((ext_vector_type(4)));
typedef __fp16 fp16x2 __attribute__((ext_vector_type(2)));

// tanh via exp + hardware rcp (1-ulp): 1 - 2*rcp(e^{2x}+1).
__device__ __forceinline__ float fast_tanh(float x) {
    float e = __expf(2.0f * x);
    return 1.0f - 2.0f * __builtin_amdgcn_rcpf(e + 1.0f);
}
__device__ __forceinline__ unsigned int pkrtz(float a, float b) {
    fp16x2 r = __builtin_amdgcn_cvt_pkrtz(a, b);
    union { fp16x2 h; unsigned int u; } v; v.h = r; return v.u;
}
__device__ __forceinline__ unsigned int pkh(float a, float b) {
    union { _Float16 h; unsigned short u; } x, y;
    x.h = (_Float16)a; y.h = (_Float16)b;
    return ((unsigned int)y.u << 16) | (unsigned int)x.u;
}
__device__ __forceinline__ unsigned short f2h(float a) {
    union { _Float16 h; unsigned short u; } x;
    x.h = (_Float16)a; return x.u;
}
__device__ __forceinline__ float fdot2u(unsigned int a, unsigned int b, float c) {
    union U { unsigned int u; h2 h; };
    U ua; ua.u = a;
    U ub; ub.u = b;
    return __builtin_amdgcn_fdot2(ua.h, ub.h, c, false);
}

// conv0 staging slot tables (round-7 HW-verified): p = 4*h + d.
#define TY64 0x11B44891A440ULL      // 3 bits per p
#define TX64 0xF120120120120120ULL  // 4 bits per p, value = tx/2
#define XST 38                      // staging row stride in dwords
#define S1SZ 8448                   // s1: 32x32 pix x 8 dw (+ slack)
#define IMGS 8

__device__ __forceinline__ void slotf(int p, int& ty, int& tx) {
    ty = (int)((TY64 >> (3 * p)) & 7);
    tx = (int)((TX64 >> (4 * p)) & 15) * 2;
}

// ---------------------------------------------------------------------------
// pack: w0mf (conv0 A, r7) + c3pk (conv3 dot2, r17) + w1a (conv1 folded A).
// w1a[(s*64+lane)*4+d]: lane(h,c) holds A[row=c][k=8h+2d(+1)].
// k=(tp=h>>1, ic=8(h&1)+2d(+1)); tap t=2s+tp in 0..29: jy=t/5, kx=t%5.
// A[m=2oc+ry][jy,kx,ic] = c1_w[oc][ic][jy-ry][kx] if 0<=jy-ry<=4, else 0.
__global__ void pack_weights(const float* __restrict__ c1_w,
                             const float* __restrict__ filters,
                             const float* __restrict__ c3_w,
                             unsigned int* __restrict__ w0mf,
                             unsigned int* __restrict__ c3pk,
                             unsigned int* __restrict__ w1a) {
    int t = blockIdx.x * blockDim.x + threadIdx.x;
    if (t < 256) {
        int d = t & 3, oc = (t >> 2) & 15, hh = (t >> 6) & 3;
        int p = 4 * hh + d, ty, tx; slotf(p, ty, tx);
        float lo = 0.f, hi = 0.f;
        if (p != 15) {
            const float* w = filters + oc * 25 + ty * 5 + tx;
            lo = w[0]; hi = (tx < 4) ? w[1] : 0.f;
        }
        w0mf[t] = pkh(lo, hi);
    } else if (t >= 4352 && t < 4352 + 480) {
        int g = t - 4352;
        int oc = g / 30, rem = g % 30, ic = rem / 5, ky = rem % 5;
        const float* w = c3_w + (oc * 6 + ic) * 25 + ky * 5;
        unsigned int* d = c3pk + (oc * 6 + ic) * 32 + ky * 6;
        d[0] = pkh(w[0], w[1]); d[1] = pkh(w[2], w[3]); d[2] = pkh(w[4], 0.f);
        d[3] = pkh(0.f, w[0]); d[4] = pkh(w[1], w[2]); d[5] = pkh(w[3], w[4]);
        if (ky == 0) {
            unsigned int* p2 = c3pk + (oc * 6 + ic) * 32;
            p2[30] = 0u; p2[31] = 0u;
        }
    } else if (t >= 4864 && t < 4864 + 3840) {
        int g = t - 4864;                 // = s*256 + lane*4 + d
        int s = g >> 8;
        int rem = g & 255;
        int lane = rem >> 2, d = rem & 3;
        int h = lane >> 4, cc = lane & 15;
        int tt = 2 * s + (h >> 1);        // 0..29
        int jy = tt / 5, kx = tt % 5;
        int icA = 8 * (h & 1) + 2 * d;
        float lo = 0.f, hi = 0.f;
        if (cc < 12) {
            int oc = cc >> 1, ry = cc & 1;
            int ky = jy - ry;
            if (ky >= 0 && ky <= 4) {
                lo = c1_w[(oc * 16 + icA) * 25 + ky * 5 + kx];
                hi = c1_w[(oc * 16 + icA + 1) * 25 + ky * 5 + kx];
            }
        }
        w1a[g] = pkh(lo, hi);
    }
}

// ---------------------------------------------------------------------------
// Front: staging (r17 P0) -> conv0 MFMA (r17 P1a) -> b16 scatter [pix][ic]
// swizzle dw^=(x&12) (r19 P1b) -> conv1 MFMA with (oc,ry) M-fold: 15 K-steps,
// ONE b128 read + ONE MFMA per step.  LDS 33792 B.
__global__ __launch_bounds__(512, 2) void lenet_front(
    const float* __restrict__ x,
    const unsigned int* __restrict__ w0mf,
    const unsigned int* __restrict__ w1a,
    const float* __restrict__ c1_b,
    float* __restrict__ out2)
{
    __shared__ __align__(16) unsigned int s1[S1SZ];

    const int b = blockIdx.x;
    const int tid = threadIdx.x;
    const int lane = tid & 63;
    const int wid = tid >> 6;
    const int h = (lane >> 4) & 3;
    const int c = lane & 15;
    const float* xb = x + (size_t)b * 1024;

    for (int i = tid; i < 1368; i += 512) s1[i] = 0u;
    if (tid < 256) s1[8192 + tid] = 0u;

    int offd[4];
#pragma unroll
    for (int d = 0; d < 4; ++d) {
        int p = 4 * h + d, ty, tx; slotf(p, ty, tx);
        offd[d] = ty * XST + tx + c;
    }
    half8 af0 = *(const half8*)(w0mf + (h * 16 + c) * 4);

    half8 afc[15];
#pragma unroll
    for (int s = 0; s < 15; s++)
        afc[s] = *(const half8*)(w1a + (s * 64 + lane) * 4);
    __syncthreads();

    // ---- P0 (r17 verbatim): input -> pair-dup f16 staging rows
    {
        int r = tid >> 4, cc = tid & 15;
        float2 v = *(const float2*)(xb + r * 32 + cc * 2);
        float vnext = __shfl(v.x, lane + 1);
        if (cc == 15) vnext = 0.f;
        unsigned int d0 = pkrtz(v.x, v.y);
        unsigned int d1 = pkrtz(v.y, vnext);
        unsigned int* row = &s1[(r + 2) * XST];
        *(uint2*)&row[2 * cc + 2] = make_uint2(d0, d1);
        if (cc == 0) row[1] = pkrtz(0.f, v.x);
    }
    __syncthreads();

    union H8 { unsigned int u[4]; half8 hv; };
    union U4H { uint4 u; half8 hv; };

    // ---- P1a (r17 verbatim): conv0 MFMA into regs
    f32x4 AC0[4], AC1[4];
#pragma unroll
    for (int yi = 0; yi < 4; ++yi) {
        const int y = 4 * wid + yi;
        const int base = y * XST;
        H8 B0, B1;
#pragma unroll
        for (int d = 0; d < 4; ++d) {
            B0.u[d] = s1[base + offd[d]];
            B1.u[d] = s1[base + 16 + offd[d]];
        }
        f32x4 z = {0.f, 0.f, 0.f, 0.f};
        AC0[yi] = __builtin_amdgcn_mfma_f32_16x16x32_f16(af0, B0.hv, z, 0, 0, 0);
        AC1[yi] = __builtin_amdgcn_mfma_f32_16x16x32_f16(af0, B1.hv, z, 0, 0, 0);
    }
    __syncthreads();

    // ---- P1b (r19 verbatim): tanh + b16 scatter, swizzle dw^=(x&12)
    {
        unsigned short* us = (unsigned short*)s1;
#pragma unroll
        for (int yi = 0; yi < 4; ++yi) {
            const int y = 4 * wid + yi;
            const int ybase = y * 256;
#pragma unroll
            for (int r = 0; r < 4; ++r) {
                int ch = 4 * h + r;
                int qq = ch >> 1, lohi = ch & 1;
                unsigned short h0 = f2h(fast_tanh(AC0[yi][r]));
                unsigned short h1 = f2h(fast_tanh(AC1[yi][r]));
                int dw0 = (ybase + c * 8 + qq) ^ (c & 12);
                int dw1 = (ybase + (16 + c) * 8 + qq) ^ (c & 12);
                us[dw0 * 2 + lohi] = h0;
                us[dw1 * 2 + lohi] = h1;
            }
        }
    }
    __syncthreads();

    // ---- P2: conv1 MFMA, (oc,ry)-folded M, 15 K-steps, 1 read + 1 MFMA each
    const bool hi2 = (h >= 2);
    const int ih4 = 4 * (h & 1);

    const float bj0 = c1_b[h < 3 ? 2 * h : 0];
    const float bj1 = c1_b[h < 3 ? 2 * h + 1 : 0];

#pragma unroll 1
    for (int q = wid; q < 28; q += 8) {
        const int py = q >> 1;
        const int xh = q & 1;
        const int x0 = 12 * xh;
        const int yy = 2 * py;
        const int xc = x0 + c;
        const int bk = yy * 256 + xc * 8 + ih4;

        f32x4 accE = {0.f, 0.f, 0.f, 0.f};
        f32x4 accO = {0.f, 0.f, 0.f, 0.f};
        __builtin_amdgcn_s_setprio(1);
#pragma unroll
        for (int s = 0; s < 15; s++) {
            const int t0 = 2 * s, t1 = 2 * s + 1;
            const int K0 = (t0 / 5) * 256 + (t0 % 5) * 8;
            const int K1 = (t1 / 5) * 256 + (t1 % 5) * 8;
            const int X0 = t0 % 5, X1 = t1 % 5;
            int Ks = hi2 ? K1 : K0;
            int txs = hi2 ? X1 : X0;
            int x2 = xc + txs;
            int dw = (bk + Ks) ^ (x2 & 12);
            U4H B;
            B.u = *(const uint4*)&s1[dw];
            if (s & 1) accO = __builtin_amdgcn_mfma_f32_16x16x32_f16(afc[s], B.hv, accO, 0, 0, 0);
            else       accE = __builtin_amdgcn_mfma_f32_16x16x32_f16(afc[s], B.hv, accE, 0, 0, 0);
        }
        __builtin_amdgcn_s_setprio(0);
        f32x4 acc = accE + accO;

        // rows 4h+r: oc = 2h + (r>>1), ry = r&1. Vertical pool in-register.
        float sA = fast_tanh(acc[0] + bj0) + fast_tanh(acc[1] + bj0);
        float sB = fast_tanh(acc[2] + bj1) + fast_tanh(acc[3] + bj1);
        sA += __shfl_xor(sA, 1);
        sB += __shfl_xor(sB, 1);
        int pq = (c >> 1) + 6 * xh;
        bool ok = (h < 3) && ((c & 1) == 0) && (xh ? (pq >= 7) : (pq <= 6));
        if (ok) {
            out2[((size_t)b * 6 + 2 * h) * 196 + py * 14 + pq]     = 0.25f * sA;
            out2[((size_t)b * 6 + 2 * h + 1) * 196 + py * 14 + pq] = 0.25f * sB;
        }
    }
}

// ---------------------------------------------------------------------------
// Back (r18 pattern, IMGS=8): a2 f32->f16; conv3 dot2 -> c5 -> fc1 -> fc2.
__global__ __launch_bounds__(256) void lenet_back(
    const float* __restrict__ out2,
    const unsigned int* __restrict__ c3pk, const float* __restrict__ c3_b,
    const float* __restrict__ c5_w, const float* __restrict__ c5_b,
    const float* __restrict__ l1_w, const float* __restrict__ l1_b,
    const float* __restrict__ l2_w, const float* __restrict__ l2_b,
    float* __restrict__ out, int B)
{
    __shared__ unsigned int a2f[IMGS][84 * 9];
    __shared__ __align__(16) float a3[IMGS][400];
    __shared__ float f5[IMGS][120];
    __shared__ float f6[IMGS][84];

    const int b0 = blockIdx.x * IMGS;
    const int tid = threadIdx.x;

    for (int i = tid; i < 588 * IMGS; i += 256) {
        int img = i / 588, rem = i % 588;
        int r = rem / 7, j = rem % 7;
        unsigned int pv = 0u;
        if (b0 + img < B) {
            const float2 v = *(const float2*)(out2 + (size_t)(b0 + img) * 1176 + r * 14 + 2 * j);
            pv = pkh(v.x, v.y);
        }
        a2f[img][r * 9 + j] = pv;
    }
    __syncthreads();

    for (int t = tid; t < 400; t += 256) {
        const int oc = t / 25;
        const int rr = t % 25;
        const int py = rr / 5, px = rr % 5;
        const int y0 = py * 2;
        float a00[IMGS], a01[IMGS], a10[IMGS], a11[IMGS];
#pragma unroll
        for (int g = 0; g < IMGS; g++) { a00[g] = 0.f; a01[g] = 0.f; a10[g] = 0.f; a11[g] = 0.f; }
#pragma unroll 1
        for (int ic = 0; ic < 6; ic++) {
            unsigned int wu[32];
            const uint4* wb = (const uint4*)(c3pk + (oc * 6 + ic) * 32);
#pragma unroll
            for (int qv = 0; qv < 8; qv++) {
                uint4 v = wb[qv];
                wu[4 * qv + 0] = v.x; wu[4 * qv + 1] = v.y;
                wu[4 * qv + 2] = v.z; wu[4 * qv + 3] = v.w;
            }
#pragma unroll
            for (int t6 = 0; t6 < 6; t6++) {
                const int rowoff = (ic * 14 + y0 + t6) * 9 + px;
#pragma unroll
                for (int g = 0; g < IMGS; g++) {
                    const unsigned int* sp = &a2f[g][rowoff];
                    unsigned int s0 = sp[0], s1v = sp[1], s2 = sp[2];
                    if (t6 < 5) {
                        const int kb = t6 * 6;
                        a00[g] = fdot2u(wu[kb + 0], s0, a00[g]);
                        a00[g] = fdot2u(wu[kb + 1], s1v, a00[g]);
                        a00[g] = fdot2u(wu[kb + 2], s2, a00[g]);
                        a01[g] = fdot2u(wu[kb + 3], s0, a01[g]);
                        a01[g] = fdot2u(wu[kb + 4], s1v, a01[g]);
                        a01[g] = fdot2u(wu[kb + 5], s2, a01[g]);
                    }
                    if (t6 >= 1) {
                        const int kb = (t6 - 1) * 6;
                        a10[g] = fdot2u(wu[kb + 0], s0, a10[g]);
                        a10[g] = fdot2u(wu[kb + 1], s1v, a10[g]);
                        a10[g] = fdot2u(wu[kb + 2], s2, a10[g]);
                        a11[g] = fdot2u(wu[kb + 3], s0, a11[g]);
                        a11[g] = fdot2u(wu[kb + 4], s1v, a11[g]);
                        a11[g] = fdot2u(wu[kb + 5], s2, a11[g]);
                    }
                }
            }
        }
        const float bb = c3_b[oc];
#pragma unroll
        for (int g = 0; g < IMGS; g++) {
            a3[g][t] = 0.25f * (fast_tanh(a00[g] + bb) + fast_tanh(a01[g] + bb) +
                                fast_tanh(a10[g] + bb) + fast_tanh(a11[g] + bb));
        }
    }
    __syncthreads();

    if (tid < 240) {
        const int o = tid >> 1;
        const int part = tid & 1;
        float acc[IMGS];
#pragma unroll
        for (int g = 0; g < IMGS; g++) acc[g] = 0.f;
        const float4* wp = (const float4*)(c5_w + (size_t)o * 400) + part * 50;
#pragma unroll 2
        for (int qv = 0; qv < 50; qv++) {
            float4 wv = wp[qv];
#pragma unroll
            for (int g = 0; g < IMGS; g++) {
                float4 av = ((const float4*)a3[g])[part * 50 + qv];
                acc[g] += wv.x * av.x + wv.y * av.y + wv.z * av.z + wv.w * av.w;
            }
        }
#pragma unroll
        for (int g = 0; g < IMGS; g++) {
            acc[g] += __shfl_xor(acc[g], 1);
            if (part == 0) f5[g][o] = fast_tanh(acc[g] + c5_b[o]);
        }
    }
    __syncthreads();

    if (tid < 84) {
        float acc[IMGS];
        const float bb = l1_b[tid];
#pragma unroll
        for (int g = 0; g < IMGS; g++) acc[g] = bb;
        const float4* wp = (const float4*)(l1_w + tid * 120);
#pragma unroll 5
        for (int qv = 0; qv < 30; qv++) {
            float4 wv = wp[qv];
#pragma unroll
            for (int g = 0; g < IMGS; g++) {
                float4 fv = ((const float4*)f5[g])[qv];
                acc[g] += wv.x * fv.x + wv.y * fv.y + wv.z * fv.z + wv.w * fv.w;
            }
        }
#pragma unroll
        for (int g = 0; g < IMGS; g++) f6[g][tid] = fast_tanh(acc[g]);
    }
    __syncthreads();

    if (tid < 10) {
        float acc[IMGS];
        const float bb = l2_b[tid];
#pragma unroll
        for (int g = 0; g < IMGS; g++) acc[g] = bb;
        const float* wp = l2_w + tid * 84;
#pragma unroll 4
        for (int qv = 0; qv < 84; qv++) {
            float w = wp[qv];
#pragma unroll
            for (int g = 0; g < IMGS; g++) acc[g] += w * f6[g][qv];
        }
#pragma unroll
        for (int g = 0; g < IMGS; g++)
            if (b0 + g < B) out[(size_t)(b0 + g) * 10 + tid] = acc[g];
    }
}

extern "C" void kernel_launch(void* const* d_in, const int* in_sizes, int n_in,
                              void* d_out, int out_size, void* d_ws, size_t ws_size,
                              hipStream_t stream) {
    const float* x       = (const float*)d_in[0];
    const float* filters = (const float*)d_in[1];
    const float* c1_w    = (const float*)d_in[2];
    const float* c1_b    = (const float*)d_in[3];
    const float* c3_w    = (const float*)d_in[4];
    const float* c3_b    = (const float*)d_in[5];
    const float* c5_w    = (const float*)d_in[6];
    const float* c5_b    = (const float*)d_in[7];
    const float* l1_w    = (const float*)d_in[8];
    const float* l1_b    = (const float*)d_in[9];
    const float* l2_w    = (const float*)d_in[10];
    const float* l2_b    = (const float*)d_in[11];
    float* out = (float*)d_out;

    const int B = in_sizes[0] / 1024;

    // ws: [w0mf @0][c3pk @17408][w1a: 3840u32 @29696 (15360B)][out2 @46080]
    unsigned int* w0mf = (unsigned int*)d_ws;
    unsigned int* c3pk = (unsigned int*)((char*)d_ws + 17408);
    unsigned int* w1a  = (unsigned int*)((char*)d_ws + 29696);
    float* out2 = (float*)((char*)d_ws + 46080);

    pack_weights<<<34, 256, 0, stream>>>(c1_w, filters, c3_w, w0mf, c3pk, w1a);
    lenet_front<<<B, 512, 0, stream>>>(x, w0mf, w1a, c1_b, out2);
    lenet_back<<<(B + IMGS - 1) / IMGS, 256, 0, stream>>>(
        out2, c3pk, c3_b, c5_w, c5_b, l1_w, l1_b, l2_w, l2_b, out, B);
}

// Round 21
// 128.541 us; speedup vs baseline: 2.4562x; 1.0585x over previous
//
#include <hip/hip_runtime.h>
#include <hip/hip_bf16.h>
#include <cstddef>

typedef _Float16 h2 __attribute__((ext_vector_type(2)));
typedef _Float16 half8 __attribute__((ext_vector_type(8)));
typedef float f32x4 __attribute__((ext_vector_type(4)));
typedef __fp16 fp16x2 __attribute__((ext_vector_type(2)));

// tanh via exp + hardware rcp (1-ulp): 1 - 2*rcp(e^{2x}+1).
__device__ __forceinline__ float fast_tanh(float x) {
    float e = __expf(2.0f * x);
    return 1.0f - 2.0f * __builtin_amdgcn_rcpf(e + 1.0f);
}
__device__ __forceinline__ unsigned int pkrtz(float a, float b) {
    fp16x2 r = __builtin_amdgcn_cvt_pkrtz(a, b);
    union { fp16x2 h; unsigned int u; } v; v.h = r; return v.u;
}
__device__ __forceinline__ unsigned int pkh(float a, float b) {
    union { _Float16 h; unsigned short u; } x, y;
    x.h = (_Float16)a; y.h = (_Float16)b;
    return ((unsigned int)y.u << 16) | (unsigned int)x.u;
}
__device__ __forceinline__ unsigned short f2h(float a) {
    union { _Float16 h; unsigned short u; } x;
    x.h = (_Float16)a; return x.u;
}
__device__ __forceinline__ float fdot2u(unsigned int a, unsigned int b, float c) {
    union U { unsigned int u; h2 h; };
    U ua; ua.u = a;
    U ub; ub.u = b;
    return __builtin_amdgcn_fdot2(ua.h, ub.h, c, false);
}

// conv0 staging slot tables (round-7 HW-verified): p = 4*h + d.
#define TY64 0x11B44891A440ULL      // 3 bits per p
#define TX64 0xF120120120120120ULL  // 4 bits per p, value = tx/2
#define XST 38                      // staging row stride in dwords
#define S1SZ 8448                   // s1: 32x32 pix x 8 dw (+ slack)
#define IMGS 4

__device__ __forceinline__ void slotf(int p, int& ty, int& tx) {
    ty = (int)((TY64 >> (3 * p)) & 7);
    tx = (int)((TX64 >> (4 * p)) & 15) * 2;
}

// ---------------------------------------------------------------------------
// pack (r20 verbatim): w0mf + c3pk + w1a (conv1 folded A)
__global__ void pack_weights(const float* __restrict__ c1_w,
                             const float* __restrict__ filters,
                             const float* __restrict__ c3_w,
                             unsigned int* __restrict__ w0mf,
                             unsigned int* __restrict__ c3pk,
                             unsigned int* __restrict__ w1a) {
    int t = blockIdx.x * blockDim.x + threadIdx.x;
    if (t < 256) {
        int d = t & 3, oc = (t >> 2) & 15, hh = (t >> 6) & 3;
        int p = 4 * hh + d, ty, tx; slotf(p, ty, tx);
        float lo = 0.f, hi = 0.f;
        if (p != 15) {
            const float* w = filters + oc * 25 + ty * 5 + tx;
            lo = w[0]; hi = (tx < 4) ? w[1] : 0.f;
        }
        w0mf[t] = pkh(lo, hi);
    } else if (t >= 4352 && t < 4352 + 480) {
        int g = t - 4352;
        int oc = g / 30, rem = g % 30, ic = rem / 5, ky = rem % 5;
        const float* w = c3_w + (oc * 6 + ic) * 25 + ky * 5;
        unsigned int* d = c3pk + (oc * 6 + ic) * 32 + ky * 6;
        d[0] = pkh(w[0], w[1]); d[1] = pkh(w[2], w[3]); d[2] = pkh(w[4], 0.f);
        d[3] = pkh(0.f, w[0]); d[4] = pkh(w[1], w[2]); d[5] = pkh(w[3], w[4]);
        if (ky == 0) {
            unsigned int* p2 = c3pk + (oc * 6 + ic) * 32;
            p2[30] = 0u; p2[31] = 0u;
        }
    } else if (t >= 4864 && t < 4864 + 3840) {
        int g = t - 4864;                 // = s*256 + lane*4 + d
        int s = g >> 8;
        int rem = g & 255;
        int lane = rem >> 2, d = rem & 3;
        int h = lane >> 4, cc = lane & 15;
        int tt = 2 * s + (h >> 1);        // 0..29
        int jy = tt / 5, kx = tt % 5;
        int icA = 8 * (h & 1) + 2 * d;
        float lo = 0.f, hi = 0.f;
        if (cc < 12) {
            int oc = cc >> 1, ry = cc & 1;
            int ky = jy - ry;
            if (ky >= 0 && ky <= 4) {
                lo = c1_w[(oc * 16 + icA) * 25 + ky * 5 + kx];
                hi = c1_w[(oc * 16 + icA + 1) * 25 + ky * 5 + kx];
            }
        }
        w1a[g] = pkh(lo, hi);
    }
}

// ---------------------------------------------------------------------------
// Front (r20 verbatim): staging -> conv0 MFMA -> b16 scatter [pix][ic]
// swizzled -> conv1 MFMA with (oc,ry) M-fold: 15 K-steps, 1 read + 1 MFMA.
__global__ __launch_bounds__(512, 2) void lenet_front(
    const float* __restrict__ x,
    const unsigned int* __restrict__ w0mf,
    const unsigned int* __restrict__ w1a,
    const float* __restrict__ c1_b,
    float* __restrict__ out2)
{
    __shared__ __align__(16) unsigned int s1[S1SZ];

    const int b = blockIdx.x;
    const int tid = threadIdx.x;
    const int lane = tid & 63;
    const int wid = tid >> 6;
    const int h = (lane >> 4) & 3;
    const int c = lane & 15;
    const float* xb = x + (size_t)b * 1024;

    for (int i = tid; i < 1368; i += 512) s1[i] = 0u;
    if (tid < 256) s1[8192 + tid] = 0u;

    int offd[4];
#pragma unroll
    for (int d = 0; d < 4; ++d) {
        int p = 4 * h + d, ty, tx; slotf(p, ty, tx);
        offd[d] = ty * XST + tx + c;
    }
    half8 af0 = *(const half8*)(w0mf + (h * 16 + c) * 4);

    half8 afc[15];
#pragma unroll
    for (int s = 0; s < 15; s++)
        afc[s] = *(const half8*)(w1a + (s * 64 + lane) * 4);
    __syncthreads();

    // P0: input -> pair-dup f16 staging rows
    {
        int r = tid >> 4, cc = tid & 15;
        float2 v = *(const float2*)(xb + r * 32 + cc * 2);
        float vnext = __shfl(v.x, lane + 1);
        if (cc == 15) vnext = 0.f;
        unsigned int d0 = pkrtz(v.x, v.y);
        unsigned int d1 = pkrtz(v.y, vnext);
        unsigned int* row = &s1[(r + 2) * XST];
        *(uint2*)&row[2 * cc + 2] = make_uint2(d0, d1);
        if (cc == 0) row[1] = pkrtz(0.f, v.x);
    }
    __syncthreads();

    union H8 { unsigned int u[4]; half8 hv; };
    union U4H { uint4 u; half8 hv; };

    // P1a: conv0 MFMA into regs
    f32x4 AC0[4], AC1[4];
#pragma unroll
    for (int yi = 0; yi < 4; ++yi) {
        const int y = 4 * wid + yi;
        const int base = y * XST;
        H8 B0, B1;
#pragma unroll
        for (int d = 0; d < 4; ++d) {
            B0.u[d] = s1[base + offd[d]];
            B1.u[d] = s1[base + 16 + offd[d]];
        }
        f32x4 z = {0.f, 0.f, 0.f, 0.f};
        AC0[yi] = __builtin_amdgcn_mfma_f32_16x16x32_f16(af0, B0.hv, z, 0, 0, 0);
        AC1[yi] = __builtin_amdgcn_mfma_f32_16x16x32_f16(af0, B1.hv, z, 0, 0, 0);
    }
    __syncthreads();

    // P1b: tanh + b16 scatter, swizzle dw^=(x&12)
    {
        unsigned short* us = (unsigned short*)s1;
#pragma unroll
        for (int yi = 0; yi < 4; ++yi) {
            const int y = 4 * wid + yi;
            const int ybase = y * 256;
#pragma unroll
            for (int r = 0; r < 4; ++r) {
                int ch = 4 * h + r;
                int qq = ch >> 1, lohi = ch & 1;
                unsigned short h0 = f2h(fast_tanh(AC0[yi][r]));
                unsigned short h1 = f2h(fast_tanh(AC1[yi][r]));
                int dw0 = (ybase + c * 8 + qq) ^ (c & 12);
                int dw1 = (ybase + (16 + c) * 8 + qq) ^ (c & 12);
                us[dw0 * 2 + lohi] = h0;
                us[dw1 * 2 + lohi] = h1;
            }
        }
    }
    __syncthreads();

    // P2: conv1 MFMA, (oc,ry)-folded M, 15 K-steps
    const bool hi2 = (h >= 2);
    const int ih4 = 4 * (h & 1);

    const float bj0 = c1_b[h < 3 ? 2 * h : 0];
    const float bj1 = c1_b[h < 3 ? 2 * h + 1 : 0];

#pragma unroll 1
    for (int q = wid; q < 28; q += 8) {
        const int py = q >> 1;
        const int xh = q & 1;
        const int x0 = 12 * xh;
        const int yy = 2 * py;
        const int xc = x0 + c;
        const int bk = yy * 256 + xc * 8 + ih4;

        f32x4 accE = {0.f, 0.f, 0.f, 0.f};
        f32x4 accO = {0.f, 0.f, 0.f, 0.f};
        __builtin_amdgcn_s_setprio(1);
#pragma unroll
        for (int s = 0; s < 15; s++) {
            const int t0 = 2 * s, t1 = 2 * s + 1;
            const int K0 = (t0 / 5) * 256 + (t0 % 5) * 8;
            const int K1 = (t1 / 5) * 256 + (t1 % 5) * 8;
            const int X0 = t0 % 5, X1 = t1 % 5;
            int Ks = hi2 ? K1 : K0;
            int txs = hi2 ? X1 : X0;
            int x2 = xc + txs;
            int dw = (bk + Ks) ^ (x2 & 12);
            U4H B;
            B.u = *(const uint4*)&s1[dw];
            if (s & 1) accO = __builtin_amdgcn_mfma_f32_16x16x32_f16(afc[s], B.hv, accO, 0, 0, 0);
            else       accE = __builtin_amdgcn_mfma_f32_16x16x32_f16(afc[s], B.hv, accE, 0, 0, 0);
        }
        __builtin_amdgcn_s_setprio(0);
        f32x4 acc = accE + accO;

        float sA = fast_tanh(acc[0] + bj0) + fast_tanh(acc[1] + bj0);
        float sB = fast_tanh(acc[2] + bj1) + fast_tanh(acc[3] + bj1);
        sA += __shfl_xor(sA, 1);
        sB += __shfl_xor(sB, 1);
        int pq = (c >> 1) + 6 * xh;
        bool ok = (h < 3) && ((c & 1) == 0) && (xh ? (pq >= 7) : (pq <= 6));
        if (ok) {
            out2[((size_t)b * 6 + 2 * h) * 196 + py * 14 + pq]     = 0.25f * sA;
            out2[((size_t)b * 6 + 2 * h + 1) * 196 + py * 14 + pq] = 0.25f * sB;
        }
    }
}

// ---------------------------------------------------------------------------
// Back (r18 verbatim, IMGS=4): a2 f32->f16; conv3 dot2 -> c5 -> fc1 -> fc2.
__global__ __launch_bounds__(256) void lenet_back(
    const float* __restrict__ out2,
    const unsigned int* __restrict__ c3pk, const float* __restrict__ c3_b,
    const float* __restrict__ c5_w, const float* __restrict__ c5_b,
    const float* __restrict__ l1_w, const float* __restrict__ l1_b,
    const float* __restrict__ l2_w, const float* __restrict__ l2_b,
    float* __restrict__ out, int B)
{
    __shared__ unsigned int a2f[IMGS][84 * 9];
    __shared__ __align__(16) float a3[IMGS][400];
    __shared__ float f5[IMGS][120];
    __shared__ float f6[IMGS][84];

    const int b0 = blockIdx.x * IMGS;
    const int tid = threadIdx.x;

    for (int i = tid; i < 588 * IMGS; i += 256) {
        int img = i / 588, rem = i % 588;
        int r = rem / 7, j = rem % 7;
        unsigned int pv = 0u;
        if (b0 + img < B) {
            const float2 v = *(const float2*)(out2 + (size_t)(b0 + img) * 1176 + r * 14 + 2 * j);
            pv = pkh(v.x, v.y);
        }
        a2f[img][r * 9 + j] = pv;
    }
    __syncthreads();

    for (int t = tid; t < 400; t += 256) {
        const int oc = t / 25;
        const int rr = t % 25;
        const int py = rr / 5, px = rr % 5;
        const int y0 = py * 2;
        float a00[IMGS], a01[IMGS], a10[IMGS], a11[IMGS];
#pragma unroll
        for (int g = 0; g < IMGS; g++) { a00[g] = 0.f; a01[g] = 0.f; a10[g] = 0.f; a11[g] = 0.f; }
#pragma unroll 1
        for (int ic = 0; ic < 6; ic++) {
            unsigned int wu[32];
            const uint4* wb = (const uint4*)(c3pk + (oc * 6 + ic) * 32);
#pragma unroll
            for (int qv = 0; qv < 8; qv++) {
                uint4 v = wb[qv];
                wu[4 * qv + 0] = v.x; wu[4 * qv + 1] = v.y;
                wu[4 * qv + 2] = v.z; wu[4 * qv + 3] = v.w;
            }
#pragma unroll
            for (int t6 = 0; t6 < 6; t6++) {
                const int rowoff = (ic * 14 + y0 + t6) * 9 + px;
#pragma unroll
                for (int g = 0; g < IMGS; g++) {
                    const unsigned int* sp = &a2f[g][rowoff];
                    unsigned int s0 = sp[0], s1v = sp[1], s2 = sp[2];
                    if (t6 < 5) {
                        const int kb = t6 * 6;
                        a00[g] = fdot2u(wu[kb + 0], s0, a00[g]);
                        a00[g] = fdot2u(wu[kb + 1], s1v, a00[g]);
                        a00[g] = fdot2u(wu[kb + 2], s2, a00[g]);
                        a01[g] = fdot2u(wu[kb + 3], s0, a01[g]);
                        a01[g] = fdot2u(wu[kb + 4], s1v, a01[g]);
                        a01[g] = fdot2u(wu[kb + 5], s2, a01[g]);
                    }
                    if (t6 >= 1) {
                        const int kb = (t6 - 1) * 6;
                        a10[g] = fdot2u(wu[kb + 0], s0, a10[g]);
                        a10[g] = fdot2u(wu[kb + 1], s1v, a10[g]);
                        a10[g] = fdot2u(wu[kb + 2], s2, a10[g]);
                        a11[g] = fdot2u(wu[kb + 3], s0, a11[g]);
                        a11[g] = fdot2u(wu[kb + 4], s1v, a11[g]);
                        a11[g] = fdot2u(wu[kb + 5], s2, a11[g]);
                    }
                }
            }
        }
        const float bb = c3_b[oc];
#pragma unroll
        for (int g = 0; g < IMGS; g++) {
            a3[g][t] = 0.25f * (fast_tanh(a00[g] + bb) + fast_tanh(a01[g] + bb) +
                                fast_tanh(a10[g] + bb) + fast_tanh(a11[g] + bb));
        }
    }
    __syncthreads();

    if (tid < 240) {
        const int o = tid >> 1;
        const int part = tid & 1;
        float acc[IMGS] = {0.f, 0.f, 0.f, 0.f};
        const float4* wp = (const float4*)(c5_w + (size_t)o * 400) + part * 50;
#pragma unroll 2
        for (int qv = 0; qv < 50; qv++) {
            float4 wv = wp[qv];
#pragma unroll
            for (int g = 0; g < IMGS; g++) {
                float4 av = ((const float4*)a3[g])[part * 50 + qv];
                acc[g] += wv.x * av.x + wv.y * av.y + wv.z * av.z + wv.w * av.w;
            }
        }
#pragma unroll
        for (int g = 0; g < IMGS; g++) {
            acc[g] += __shfl_xor(acc[g], 1);
            if (part == 0) f5[g][o] = fast_tanh(acc[g] + c5_b[o]);
        }
    }
    __syncthreads();

    if (tid < 84) {
        float acc[IMGS];
        const float bb = l1_b[tid];
#pragma unroll
        for (int g = 0; g < IMGS; g++) acc[g] = bb;
        const float4* wp = (const float4*)(l1_w + tid * 120);
#pragma unroll 5
        for (int qv = 0; qv < 30; qv++) {
            float4 wv = wp[qv];
#pragma unroll
            for (int g = 0; g < IMGS; g++) {
                float4 fv = ((const float4*)f5[g])[qv];
                acc[g] += wv.x * fv.x + wv.y * fv.y + wv.z * fv.z + wv.w * fv.w;
            }
        }
#pragma unroll
        for (int g = 0; g < IMGS; g++) f6[g][tid] = fast_tanh(acc[g]);
    }
    __syncthreads();

    if (tid < 10) {
        float acc[IMGS];
        const float bb = l2_b[tid];
#pragma unroll
        for (int g = 0; g < IMGS; g++) acc[g] = bb;
        const float* wp = l2_w + tid * 84;
#pragma unroll 4
        for (int qv = 0; qv < 84; qv++) {
            float w = wp[qv];
#pragma unroll
            for (int g = 0; g < IMGS; g++) acc[g] += w * f6[g][qv];
        }
#pragma unroll
        for (int g = 0; g < IMGS; g++)
            if (b0 + g < B) out[(size_t)(b0 + g) * 10 + tid] = acc[g];
    }
}

extern "C" void kernel_launch(void* const* d_in, const int* in_sizes, int n_in,
                              void* d_out, int out_size, void* d_ws, size_t ws_size,
                              hipStream_t stream) {
    const float* x       = (const float*)d_in[0];
    const float* filters = (const float*)d_in[1];
    const float* c1_w    = (const float*)d_in[2];
    const float* c1_b    = (const float*)d_in[3];
    const float* c3_w    = (const float*)d_in[4];
    const float* c3_b    = (const float*)d_in[5];
    const float* c5_w    = (const float*)d_in[6];
    const float* c5_b    = (const float*)d_in[7];
    const float* l1_w    = (const float*)d_in[8];
    const float* l1_b    = (const float*)d_in[9];
    const float* l2_w    = (const float*)d_in[10];
    const float* l2_b    = (const float*)d_in[11];
    float* out = (float*)d_out;

    const int B = in_sizes[0] / 1024;

    // ws: [w0mf @0][c3pk @17408][w1a: 3840u32 @29696 (15360B)][out2 @46080]
    unsigned int* w0mf = (unsigned int*)d_ws;
    unsigned int* c3pk = (unsigned int*)((char*)d_ws + 17408);
    unsigned int* w1a  = (unsigned int*)((char*)d_ws + 29696);
    float* out2 = (float*)((char*)d_ws + 46080);

    pack_weights<<<34, 256, 0, stream>>>(c1_w, filters, c3_w, w0mf, c3pk, w1a);
    lenet_front<<<B, 512, 0, stream>>>(x, w0mf, w1a, c1_b, out2);
    lenet_back<<<(B + IMGS - 1) / IMGS, 256, 0, stream>>>(
        out2, c3pk, c3_b, c5_w, c5_b, l1_w, l1_b, l2_w, l2_b, out, B);
}

// Round 22
// 113.410 us; speedup vs baseline: 2.7839x; 1.1334x over previous
//
#include <hip/hip_runtime.h>
#include <hip/hip_bf16.h>
#include <cstddef>

typedef _Float16 h2 __attribute__((ext_vector_type(2)));
typedef _Float16 half8 __attribute__((ext_vector_type(8)));
typedef float f32x4 __attribute__((ext_vector_type(4)));
typedef __fp16 fp16x2 __attribute__((ext_vector_type(2)));

// tanh via exp + hardware rcp (1-ulp): 1 - 2*rcp(e^{2x}+1).
__device__ __forceinline__ float fast_tanh(float x) {
    float e = __expf(2.0f * x);
    return 1.0f - 2.0f * __builtin_amdgcn_rcpf(e + 1.0f);
}
__device__ __forceinline__ unsigned int pkrtz(float a, float b) {
    fp16x2 r = __builtin_amdgcn_cvt_pkrtz(a, b);
    union { fp16x2 h; unsigned int u; } v; v.h = r; return v.u;
}
__device__ __forceinline__ unsigned int pkh(float a, float b) {
    union { _Float16 h; unsigned short u; } x, y;
    x.h = (_Float16)a; y.h = (_Float16)b;
    return ((unsigned int)y.u << 16) | (unsigned int)x.u;
}
__device__ __forceinline__ unsigned short f2h(float a) {
    union { _Float16 h; unsigned short u; } x;
    x.h = (_Float16)a; return x.u;
}
__device__ __forceinline__ float fdot2u(unsigned int a, unsigned int b, float c) {
    union U { unsigned int u; h2 h; };
    U ua; ua.u = a;
    U ub; ub.u = b;
    return __builtin_amdgcn_fdot2(ua.h, ub.h, c, false);
}

// conv0 staging slot tables (round-7 HW-verified): p = 4*h + d.
#define TY64 0x11B44891A440ULL      // 3 bits per p
#define TX64 0xF120120120120120ULL  // 4 bits per p, value = tx/2
#define XST 38                      // staging row stride in dwords
#define S1SZ 8448                   // s1: 32x32 pix x 8 dw (+ slack)
#define IMGS 4

__device__ __forceinline__ void slotf(int p, int& ty, int& tx) {
    ty = (int)((TY64 >> (3 * p)) & 7);
    tx = (int)((TX64 >> (4 * p)) & 15) * 2;
}

// ---------------------------------------------------------------------------
// pack: w0mf + c3pk + w1a (r20 verbatim) + c5pk/l1pk (f16 pairs)
__global__ void pack_weights(const float* __restrict__ c1_w,
                             const float* __restrict__ filters,
                             const float* __restrict__ c3_w,
                             const float* __restrict__ c5_w,
                             const float* __restrict__ l1_w,
                             unsigned int* __restrict__ w0mf,
                             unsigned int* __restrict__ c3pk,
                             unsigned int* __restrict__ w1a,
                             unsigned int* __restrict__ c5pk,
                             unsigned int* __restrict__ l1pk) {
    int t = blockIdx.x * blockDim.x + threadIdx.x;
    if (t < 256) {
        int d = t & 3, oc = (t >> 2) & 15, hh = (t >> 6) & 3;
        int p = 4 * hh + d, ty, tx; slotf(p, ty, tx);
        float lo = 0.f, hi = 0.f;
        if (p != 15) {
            const float* w = filters + oc * 25 + ty * 5 + tx;
            lo = w[0]; hi = (tx < 4) ? w[1] : 0.f;
        }
        w0mf[t] = pkh(lo, hi);
    } else if (t >= 4352 && t < 4352 + 480) {
        int g = t - 4352;
        int oc = g / 30, rem = g % 30, ic = rem / 5, ky = rem % 5;
        const float* w = c3_w + (oc * 6 + ic) * 25 + ky * 5;
        unsigned int* d = c3pk + (oc * 6 + ic) * 32 + ky * 6;
        d[0] = pkh(w[0], w[1]); d[1] = pkh(w[2], w[3]); d[2] = pkh(w[4], 0.f);
        d[3] = pkh(0.f, w[0]); d[4] = pkh(w[1], w[2]); d[5] = pkh(w[3], w[4]);
        if (ky == 0) {
            unsigned int* p2 = c3pk + (oc * 6 + ic) * 32;
            p2[30] = 0u; p2[31] = 0u;
        }
    } else if (t >= 4864 && t < 4864 + 3840) {
        int g = t - 4864;                 // = s*256 + lane*4 + d
        int s = g >> 8;
        int rem = g & 255;
        int lane = rem >> 2, d = rem & 3;
        int h = lane >> 4, cc = lane & 15;
        int tt = 2 * s + (h >> 1);        // 0..29
        int jy = tt / 5, kx = tt % 5;
        int icA = 8 * (h & 1) + 2 * d;
        float lo = 0.f, hi = 0.f;
        if (cc < 12) {
            int oc = cc >> 1, ry = cc & 1;
            int ky = jy - ry;
            if (ky >= 0 && ky <= 4) {
                lo = c1_w[(oc * 16 + icA) * 25 + ky * 5 + kx];
                hi = c1_w[(oc * 16 + icA + 1) * 25 + ky * 5 + kx];
            }
        }
        w1a[g] = pkh(lo, hi);
    } else if (t >= 8960 && t < 8960 + 24000) {
        int g = t - 8960;
        int o = g / 200, j = g % 200;
        c5pk[o * 200 + j] = pkh(c5_w[o * 400 + 2 * j], c5_w[o * 400 + 2 * j + 1]);
    } else if (t >= 33280 && t < 33280 + 5040) {
        int g = t - 33280;
        int o = g / 60, j = g % 60;
        l1pk[o * 60 + j] = pkh(l1_w[o * 120 + 2 * j], l1_w[o * 120 + 2 * j + 1]);
    }
}

// ---------------------------------------------------------------------------
// Front (r21 + P1b dword-pack stores): staging -> conv0 MFMA -> scatter
// [pix][ic] swizzled -> conv1 MFMA (oc,ry)-fold, 15 K-steps.
__global__ __launch_bounds__(512, 2) void lenet_front(
    const float* __restrict__ x,
    const unsigned int* __restrict__ w0mf,
    const unsigned int* __restrict__ w1a,
    const float* __restrict__ c1_b,
    float* __restrict__ out2)
{
    __shared__ __align__(16) unsigned int s1[S1SZ];

    const int b = blockIdx.x;
    const int tid = threadIdx.x;
    const int lane = tid & 63;
    const int wid = tid >> 6;
    const int h = (lane >> 4) & 3;
    const int c = lane & 15;
    const float* xb = x + (size_t)b * 1024;

    for (int i = tid; i < 1368; i += 512) s1[i] = 0u;
    if (tid < 256) s1[8192 + tid] = 0u;

    int offd[4];
#pragma unroll
    for (int d = 0; d < 4; ++d) {
        int p = 4 * h + d, ty, tx; slotf(p, ty, tx);
        offd[d] = ty * XST + tx + c;
    }
    half8 af0 = *(const half8*)(w0mf + (h * 16 + c) * 4);

    half8 afc[15];
#pragma unroll
    for (int s = 0; s < 15; s++)
        afc[s] = *(const half8*)(w1a + (s * 64 + lane) * 4);
    __syncthreads();

    // P0: input -> pair-dup f16 staging rows
    {
        int r = tid >> 4, cc = tid & 15;
        float2 v = *(const float2*)(xb + r * 32 + cc * 2);
        float vnext = __shfl(v.x, lane + 1);
        if (cc == 15) vnext = 0.f;
        unsigned int d0 = pkrtz(v.x, v.y);
        unsigned int d1 = pkrtz(v.y, vnext);
        unsigned int* row = &s1[(r + 2) * XST];
        *(uint2*)&row[2 * cc + 2] = make_uint2(d0, d1);
        if (cc == 0) row[1] = pkrtz(0.f, v.x);
    }
    __syncthreads();

    union H8 { unsigned int u[4]; half8 hv; };
    union U4H { uint4 u; half8 hv; };

    // P1a: conv0 MFMA into regs
    f32x4 AC0[4], AC1[4];
#pragma unroll
    for (int yi = 0; yi < 4; ++yi) {
        const int y = 4 * wid + yi;
        const int base = y * XST;
        H8 B0, B1;
#pragma unroll
        for (int d = 0; d < 4; ++d) {
            B0.u[d] = s1[base + offd[d]];
            B1.u[d] = s1[base + 16 + offd[d]];
        }
        f32x4 z = {0.f, 0.f, 0.f, 0.f};
        AC0[yi] = __builtin_amdgcn_mfma_f32_16x16x32_f16(af0, B0.hv, z, 0, 0, 0);
        AC1[yi] = __builtin_amdgcn_mfma_f32_16x16x32_f16(af0, B1.hv, z, 0, 0, 0);
    }
    __syncthreads();

    // P1b: tanh + PAIRED dword stores (values bit-identical to r21):
    // rows r=2pr,2pr+1 share dword qq=2h+pr (lo/hi); col 16+c is dwA+128.
    {
#pragma unroll
        for (int yi = 0; yi < 4; ++yi) {
            const int y = 4 * wid + yi;
            const int ybase = y * 256;
#pragma unroll
            for (int pr = 0; pr < 2; ++pr) {
                unsigned int w0 = pkh(fast_tanh(AC0[yi][2 * pr]),
                                      fast_tanh(AC0[yi][2 * pr + 1]));
                unsigned int w1 = pkh(fast_tanh(AC1[yi][2 * pr]),
                                      fast_tanh(AC1[yi][2 * pr + 1]));
                int dwA = (ybase + c * 8 + 2 * h + pr) ^ (c & 12);
                s1[dwA] = w0;
                s1[dwA + 128] = w1;
            }
        }
    }
    __syncthreads();

    // P2: conv1 MFMA, (oc,ry)-folded M, 15 K-steps
    const bool hi2 = (h >= 2);
    const int ih4 = 4 * (h & 1);

    const float bj0 = c1_b[h < 3 ? 2 * h : 0];
    const float bj1 = c1_b[h < 3 ? 2 * h + 1 : 0];

#pragma unroll 1
    for (int q = wid; q < 28; q += 8) {
        const int py = q >> 1;
        const int xh = q & 1;
        const int x0 = 12 * xh;
        const int yy = 2 * py;
        const int xc = x0 + c;
        const int bk = yy * 256 + xc * 8 + ih4;

        f32x4 accE = {0.f, 0.f, 0.f, 0.f};
        f32x4 accO = {0.f, 0.f, 0.f, 0.f};
        __builtin_amdgcn_s_setprio(1);
#pragma unroll
        for (int s = 0; s < 15; s++) {
            const int t0 = 2 * s, t1 = 2 * s + 1;
            const int K0 = (t0 / 5) * 256 + (t0 % 5) * 8;
            const int K1 = (t1 / 5) * 256 + (t1 % 5) * 8;
            const int X0 = t0 % 5, X1 = t1 % 5;
            int Ks = hi2 ? K1 : K0;
            int txs = hi2 ? X1 : X0;
            int x2 = xc + txs;
            int dw = (bk + Ks) ^ (x2 & 12);
            U4H B;
            B.u = *(const uint4*)&s1[dw];
            if (s & 1) accO = __builtin_amdgcn_mfma_f32_16x16x32_f16(afc[s], B.hv, accO, 0, 0, 0);
            else       accE = __builtin_amdgcn_mfma_f32_16x16x32_f16(afc[s], B.hv, accE, 0, 0, 0);
        }
        __builtin_amdgcn_s_setprio(0);
        f32x4 acc = accE + accO;

        float sA = fast_tanh(acc[0] + bj0) + fast_tanh(acc[1] + bj0);
        float sB = fast_tanh(acc[2] + bj1) + fast_tanh(acc[3] + bj1);
        sA += __shfl_xor(sA, 1);
        sB += __shfl_xor(sB, 1);
        int pq = (c >> 1) + 6 * xh;
        bool ok = (h < 3) && ((c & 1) == 0) && (xh ? (pq >= 7) : (pq <= 6));
        if (ok) {
            out2[((size_t)b * 6 + 2 * h) * 196 + py * 14 + pq]     = 0.25f * sA;
            out2[((size_t)b * 6 + 2 * h + 1) * 196 + py * 14 + pq] = 0.25f * sB;
        }
    }
}

// ---------------------------------------------------------------------------
// Back (r18 structure, IMGS=4; c5/fc1 in f16 dot2): a2 f32->f16;
// conv3 dot2 -> a3 f16 -> c5 (f16) -> fc1 (f16) -> fc2 (f32).
__global__ __launch_bounds__(256) void lenet_back(
    const float* __restrict__ out2,
    const unsigned int* __restrict__ c3pk, const float* __restrict__ c3_b,
    const unsigned int* __restrict__ c5pk, const float* __restrict__ c5_b,
    const unsigned int* __restrict__ l1pk, const float* __restrict__ l1_b,
    const float* __restrict__ l2_w, const float* __restrict__ l2_b,
    float* __restrict__ out, int B)
{
    __shared__ unsigned int a2f[IMGS][84 * 9];
    __shared__ __align__(16) unsigned short a3h[IMGS][400];
    __shared__ __align__(16) unsigned short f5h[IMGS][120];
    __shared__ float f6[IMGS][84];

    const int b0 = blockIdx.x * IMGS;
    const int tid = threadIdx.x;

    for (int i = tid; i < 588 * IMGS; i += 256) {
        int img = i / 588, rem = i % 588;
        int r = rem / 7, j = rem % 7;
        unsigned int pv = 0u;
        if (b0 + img < B) {
            const float2 v = *(const float2*)(out2 + (size_t)(b0 + img) * 1176 + r * 14 + 2 * j);
            pv = pkh(v.x, v.y);
        }
        a2f[img][r * 9 + j] = pv;
    }
    __syncthreads();

    for (int t = tid; t < 400; t += 256) {
        const int oc = t / 25;
        const int rr = t % 25;
        const int py = rr / 5, px = rr % 5;
        const int y0 = py * 2;
        float a00[IMGS], a01[IMGS], a10[IMGS], a11[IMGS];
#pragma unroll
        for (int g = 0; g < IMGS; g++) { a00[g] = 0.f; a01[g] = 0.f; a10[g] = 0.f; a11[g] = 0.f; }
#pragma unroll 1
        for (int ic = 0; ic < 6; ic++) {
            unsigned int wu[32];
            const uint4* wb = (const uint4*)(c3pk + (oc * 6 + ic) * 32);
#pragma unroll
            for (int qv = 0; qv < 8; qv++) {
                uint4 v = wb[qv];
                wu[4 * qv + 0] = v.x; wu[4 * qv + 1] = v.y;
                wu[4 * qv + 2] = v.z; wu[4 * qv + 3] = v.w;
            }
#pragma unroll
            for (int t6 = 0; t6 < 6; t6++) {
                const int rowoff = (ic * 14 + y0 + t6) * 9 + px;
#pragma unroll
                for (int g = 0; g < IMGS; g++) {
                    const unsigned int* sp = &a2f[g][rowoff];
                    unsigned int s0 = sp[0], s1v = sp[1], s2 = sp[2];
                    if (t6 < 5) {
                        const int kb = t6 * 6;
                        a00[g] = fdot2u(wu[kb + 0], s0, a00[g]);
                        a00[g] = fdot2u(wu[kb + 1], s1v, a00[g]);
                        a00[g] = fdot2u(wu[kb + 2], s2, a00[g]);
                        a01[g] = fdot2u(wu[kb + 3], s0, a01[g]);
                        a01[g] = fdot2u(wu[kb + 4], s1v, a01[g]);
                        a01[g] = fdot2u(wu[kb + 5], s2, a01[g]);
                    }
                    if (t6 >= 1) {
                        const int kb = (t6 - 1) * 6;
                        a10[g] = fdot2u(wu[kb + 0], s0, a10[g]);
                        a10[g] = fdot2u(wu[kb + 1], s1v, a10[g]);
                        a10[g] = fdot2u(wu[kb + 2], s2, a10[g]);
                        a11[g] = fdot2u(wu[kb + 3], s0, a11[g]);
                        a11[g] = fdot2u(wu[kb + 4], s1v, a11[g]);
                        a11[g] = fdot2u(wu[kb + 5], s2, a11[g]);
                    }
                }
            }
        }
        const float bb = c3_b[oc];
#pragma unroll
        for (int g = 0; g < IMGS; g++) {
            a3h[g][t] = f2h(0.25f * (fast_tanh(a00[g] + bb) + fast_tanh(a01[g] + bb) +
                                     fast_tanh(a10[g] + bb) + fast_tanh(a11[g] + bb)));
        }
    }
    __syncthreads();

    // c5: 120 outputs x 2 threads, f16 dot2 (100 fdot2/part over 25 uint4)
    if (tid < 240) {
        const int o = tid >> 1;
        const int part = tid & 1;
        float acc[IMGS] = {0.f, 0.f, 0.f, 0.f};
        const uint4* wp = (const uint4*)(c5pk + o * 200 + part * 100);
#pragma unroll 5
        for (int qv = 0; qv < 25; qv++) {
            uint4 wv = wp[qv];
#pragma unroll
            for (int g = 0; g < IMGS; g++) {
                uint4 av = ((const uint4*)a3h[g])[part * 25 + qv];
                acc[g] = fdot2u(wv.x, av.x, acc[g]);
                acc[g] = fdot2u(wv.y, av.y, acc[g]);
                acc[g] = fdot2u(wv.z, av.z, acc[g]);
                acc[g] = fdot2u(wv.w, av.w, acc[g]);
            }
        }
#pragma unroll
        for (int g = 0; g < IMGS; g++) {
            acc[g] += __shfl_xor(acc[g], 1);
            if (part == 0) f5h[g][o] = f2h(fast_tanh(acc[g] + c5_b[o]));
        }
    }
    __syncthreads();

    // fc1: 84 outputs, f16 dot2 (15 uint4 = 120 f16)
    if (tid < 84) {
        float acc[IMGS];
        const float bb = l1_b[tid];
#pragma unroll
        for (int g = 0; g < IMGS; g++) acc[g] = bb;
        const uint4* wp = (const uint4*)(l1pk + tid * 60);
#pragma unroll 5
        for (int qv = 0; qv < 15; qv++) {
            uint4 wv = wp[qv];
#pragma unroll
            for (int g = 0; g < IMGS; g++) {
                uint4 fv = ((const uint4*)f5h[g])[qv];
                acc[g] = fdot2u(wv.x, fv.x, acc[g]);
                acc[g] = fdot2u(wv.y, fv.y, acc[g]);
                acc[g] = fdot2u(wv.z, fv.z, acc[g]);
                acc[g] = fdot2u(wv.w, fv.w, acc[g]);
            }
        }
#pragma unroll
        for (int g = 0; g < IMGS; g++) f6[g][tid] = fast_tanh(acc[g]);
    }
    __syncthreads();

    // fc2: f32 (tiny)
    if (tid < 10) {
        float acc[IMGS];
        const float bb = l2_b[tid];
#pragma unroll
        for (int g = 0; g < IMGS; g++) acc[g] = bb;
        const float* wp = l2_w + tid * 84;
#pragma unroll 4
        for (int qv = 0; qv < 84; qv++) {
            float w = wp[qv];
#pragma unroll
            for (int g = 0; g < IMGS; g++) acc[g] += w * f6[g][qv];
        }
#pragma unroll
        for (int g = 0; g < IMGS; g++)
            if (b0 + g < B) out[(size_t)(b0 + g) * 10 + tid] = acc[g];
    }
}

extern "C" void kernel_launch(void* const* d_in, const int* in_sizes, int n_in,
                              void* d_out, int out_size, void* d_ws, size_t ws_size,
                              hipStream_t stream) {
    const float* x       = (const float*)d_in[0];
    const float* filters = (const float*)d_in[1];
    const float* c1_w    = (const float*)d_in[2];
    const float* c1_b    = (const float*)d_in[3];
    const float* c3_w    = (const float*)d_in[4];
    const float* c3_b    = (const float*)d_in[5];
    const float* c5_w    = (const float*)d_in[6];
    const float* c5_b    = (const float*)d_in[7];
    const float* l1_w    = (const float*)d_in[8];
    const float* l1_b    = (const float*)d_in[9];
    const float* l2_w    = (const float*)d_in[10];
    const float* l2_b    = (const float*)d_in[11];
    float* out = (float*)d_out;

    const int B = in_sizes[0] / 1024;

    // ws: [w0mf @0][c3pk @17408][w1a @29696 (15360B)][c5pk @46080 (96000B)]
    //     [l1pk @142336 (20160B)][out2 @163840]
    unsigned int* w0mf = (unsigned int*)d_ws;
    unsigned int* c3pk = (unsigned int*)((char*)d_ws + 17408);
    unsigned int* w1a  = (unsigned int*)((char*)d_ws + 29696);
    unsigned int* c5pk = (unsigned int*)((char*)d_ws + 46080);
    unsigned int* l1pk = (unsigned int*)((char*)d_ws + 142336);
    float* out2 = (float*)((char*)d_ws + 163840);

    pack_weights<<<150, 256, 0, stream>>>(c1_w, filters, c3_w, c5_w, l1_w,
                                          w0mf, c3pk, w1a, c5pk, l1pk);
    lenet_front<<<B, 512, 0, stream>>>(x, w0mf, w1a, c1_b, out2);
    lenet_back<<<(B + IMGS - 1) / IMGS, 256, 0, stream>>>(
        out2, c3pk, c3_b, c5pk, c5_b, l1pk, l1_b, l2_w, l2_b, out, B);
}